// Round 1
// baseline (2382.939 us; speedup 1.0000x reference)
//
#include <hip/hip_runtime.h>

#define N_NODES 500000
#define NGRAPH  64
#define FDIM    16

// ---------- per-node projections: a = x.w_neigh0, s = x.w_self0 ----------
__global__ void proj_kernel(const float* __restrict__ x,
                            const float* __restrict__ wn,   // [16]
                            const float* __restrict__ wsf,  // [16]
                            float* __restrict__ a,
                            float* __restrict__ s) {
    int i = blockIdx.x * blockDim.x + threadIdx.x;
    if (i >= N_NODES) return;
    const float4* xr = (const float4*)(x + (size_t)i * FDIM);
    float4 v0 = xr[0], v1 = xr[1], v2 = xr[2], v3 = xr[3];
    const float4* n4 = (const float4*)wn;
    const float4* s4 = (const float4*)wsf;
    float4 n0 = n4[0], n1 = n4[1], n2 = n4[2], n3 = n4[3];
    float4 w0 = s4[0], w1 = s4[1], w2 = s4[2], w3 = s4[3];
    float an = v0.x*n0.x + v0.y*n0.y + v0.z*n0.z + v0.w*n0.w
             + v1.x*n1.x + v1.y*n1.y + v1.z*n1.z + v1.w*n1.w
             + v2.x*n2.x + v2.y*n2.y + v2.z*n2.z + v2.w*n2.w
             + v3.x*n3.x + v3.y*n3.y + v3.z*n3.z + v3.w*n3.w;
    float as = v0.x*w0.x + v0.y*w0.y + v0.z*w0.z + v0.w*w0.w
             + v1.x*w1.x + v1.y*w1.y + v1.z*w1.z + v1.w*w1.w
             + v2.x*w2.x + v2.y*w2.y + v2.z*w2.z + v2.w*w2.w
             + v3.x*w3.x + v3.y*w3.y + v3.z*w3.z + v3.w*w3.w;
    a[i] = an;
    s[i] = as;
}

// ---------- edge pass: agg[dst] += h[src] * ew * scale ----------
__global__ void edge_pass(const int*   __restrict__ src,
                          const int*   __restrict__ dst,
                          const float* __restrict__ ew,
                          const float* __restrict__ h,
                          float*       __restrict__ agg,
                          const float* __restrict__ wnp,  // scalar weight or nullptr (=1)
                          int E) {
    float scale = wnp ? wnp[0] : 1.0f;
    int nv = E >> 2;
    const int4*   s4 = (const int4*)src;
    const int4*   d4 = (const int4*)dst;
    const float4* w4 = (const float4*)ew;
    int stride = gridDim.x * blockDim.x;
    for (int i = blockIdx.x * blockDim.x + threadIdx.x; i < nv; i += stride) {
        int4   ss = s4[i];
        int4   dd = d4[i];
        float4 ww = w4[i];
        float m0 = h[ss.x] * (ww.x * scale);
        float m1 = h[ss.y] * (ww.y * scale);
        float m2 = h[ss.z] * (ww.z * scale);
        float m3 = h[ss.w] * (ww.w * scale);
        atomicAdd(&agg[dd.x], m0);
        atomicAdd(&agg[dd.y], m1);
        atomicAdd(&agg[dd.z], m2);
        atomicAdd(&agg[dd.w], m3);
    }
    // tail (E may not be multiple of 4)
    int tail = nv << 2;
    for (int i = tail + blockIdx.x * blockDim.x + threadIdx.x; i < E; i += stride)
        atomicAdd(&agg[dst[i]], h[src[i]] * ew[i] * scale);
}

// ---------- node update: h_out = relu(agg + b + selfv*wscale) ----------
__global__ void node_update(const float* __restrict__ agg,
                            const float* __restrict__ selfv,
                            const float* __restrict__ bp,    // scalar bias
                            const float* __restrict__ wsp,   // scalar self weight or nullptr (=1)
                            float* __restrict__ hout) {
    int i = blockIdx.x * blockDim.x + threadIdx.x;
    if (i >= N_NODES) return;
    float b  = bp[0];
    float wsc = wsp ? wsp[0] : 1.0f;
    float v = agg[i] + b + selfv[i] * wsc;
    hout[i] = fmaxf(v, 0.0f);
}

// ---------- per-graph sum (graph_id sorted) ----------
__global__ void graph_sum(const float* __restrict__ h,
                          const int*   __restrict__ gid,
                          float* __restrict__ hg) {
    __shared__ float loc[NGRAPH];
    int t = threadIdx.x;
    if (t < NGRAPH) loc[t] = 0.0f;
    __syncthreads();
    int stride = gridDim.x * blockDim.x;
    for (int i = blockIdx.x * blockDim.x + t; i < N_NODES; i += stride)
        atomicAdd(&loc[gid[i]], h[i]);
    __syncthreads();
    if (t < NGRAPH) atomicAdd(&hg[t], loc[t]);
}

// ---------- head MLP + log_softmax ----------
__global__ void head_kernel(const float* __restrict__ hg,
                            const float* __restrict__ fc1w,  // [8]
                            const float* __restrict__ fc1b,  // [8]
                            const float* __restrict__ outw,  // [4,8]
                            const float* __restrict__ outb,  // [4]
                            float* __restrict__ out) {
    int g = threadIdx.x;
    if (g >= NGRAPH) return;
    float v = hg[g];
    float t[8];
#pragma unroll
    for (int j = 0; j < 8; ++j) {
        float z = (v * fc1w[j] + fc1b[j]) * 1000.0f;
        t[j] = 1.0f / (1.0f + expf(-z));
    }
    float o[4];
#pragma unroll
    for (int k = 0; k < 4; ++k) {
        float acc = outb[k];
#pragma unroll
        for (int j = 0; j < 8; ++j) acc += t[j] * outw[k * 8 + j];
        o[k] = fmaxf(acc, 0.0f);
    }
    float m = fmaxf(fmaxf(o[0], o[1]), fmaxf(o[2], o[3]));
    float se = 0.0f;
#pragma unroll
    for (int k = 0; k < 4; ++k) se += expf(o[k] - m);
    float lse = m + logf(se);
#pragma unroll
    for (int k = 0; k < 4; ++k) out[g * 4 + k] = o[k] - lse;
}

extern "C" void kernel_launch(void* const* d_in, const int* in_sizes, int n_in,
                              void* d_out, int out_size, void* d_ws, size_t ws_size,
                              hipStream_t stream) {
    const float* x    = (const float*)d_in[0];
    const int*   src  = (const int*)  d_in[1];
    const int*   dst  = (const int*)  d_in[2];
    const int*   gid  = (const int*)  d_in[3];
    const float* ew   = (const float*)d_in[4];
    // d_in[5] = num_graphs (=64, hardcoded)
    const float* wn0  = (const float*)d_in[6];
    const float* b0   = (const float*)d_in[7];
    const float* ws0  = (const float*)d_in[8];
    const float* wn1  = (const float*)d_in[9];
    const float* b1   = (const float*)d_in[10];
    const float* ws1  = (const float*)d_in[11];
    const float* wn2  = (const float*)d_in[12];
    const float* b2   = (const float*)d_in[13];
    const float* ws2  = (const float*)d_in[14];
    const float* fc1w = (const float*)d_in[15];
    const float* fc1b = (const float*)d_in[16];
    const float* outw = (const float*)d_in[17];
    const float* outb = (const float*)d_in[18];
    int E = in_sizes[1];

    float* wsb = (float*)d_ws;
    float* a   = wsb;                    // N
    float* s   = wsb + 1 * N_NODES;      // N
    float* agg = wsb + 2 * N_NODES;      // N
    float* h   = wsb + 3 * N_NODES;      // N
    float* hg  = wsb + 4 * N_NODES;      // 64

    const int BLK = 256;
    int nodeGrid = (N_NODES + BLK - 1) / BLK;
    int edgeGrid = 4096;

    // layer 0 projections
    proj_kernel<<<nodeGrid, BLK, 0, stream>>>(x, wn0, ws0, a, s);

    // layer 0: agg = segsum(a[src]*ew); h = relu(agg + b0 + s)
    hipMemsetAsync(agg, 0, (size_t)N_NODES * sizeof(float), stream);
    edge_pass<<<edgeGrid, BLK, 0, stream>>>(src, dst, ew, a, agg, nullptr, E);
    node_update<<<nodeGrid, BLK, 0, stream>>>(agg, s, b0, nullptr, h);

    // layer 1: h = relu(segsum(h[src]*ew*wn1) + b1 + h*ws1)
    hipMemsetAsync(agg, 0, (size_t)N_NODES * sizeof(float), stream);
    edge_pass<<<edgeGrid, BLK, 0, stream>>>(src, dst, ew, h, agg, wn1, E);
    node_update<<<nodeGrid, BLK, 0, stream>>>(agg, h, b1, ws1, h);

    // layer 2
    hipMemsetAsync(agg, 0, (size_t)N_NODES * sizeof(float), stream);
    edge_pass<<<edgeGrid, BLK, 0, stream>>>(src, dst, ew, h, agg, wn2, E);
    node_update<<<nodeGrid, BLK, 0, stream>>>(agg, h, b2, ws2, h);

    // readout
    hipMemsetAsync(hg, 0, NGRAPH * sizeof(float), stream);
    graph_sum<<<512, BLK, 0, stream>>>(h, gid, hg);
    head_kernel<<<1, 64, 0, stream>>>(hg, fc1w, fc1b, outw, outb, (float*)d_out);
}

// Round 2
// 722.408 us; speedup vs baseline: 3.2986x; 3.2986x over previous
//
#include <hip/hip_runtime.h>

#define N_NODES 500000
#define NGRAPH  64
#define FDIM    16
#define NPB     1024                 // nodes per bin (power of 2)
#define NBINS   489                  // ceil(N_NODES / NPB)
#define NBLK    1024                 // binning blocks
typedef unsigned int u32;

// ---------- per-node projections: a = x.w_neigh0, s = x.w_self0 ----------
__global__ void proj_kernel(const float* __restrict__ x,
                            const float* __restrict__ wn,   // [16]
                            const float* __restrict__ wsf,  // [16]
                            float* __restrict__ a,
                            float* __restrict__ s) {
    int i = blockIdx.x * blockDim.x + threadIdx.x;
    if (i >= N_NODES) return;
    const float4* xr = (const float4*)(x + (size_t)i * FDIM);
    float4 v0 = xr[0], v1 = xr[1], v2 = xr[2], v3 = xr[3];
    const float4* n4 = (const float4*)wn;
    const float4* s4 = (const float4*)wsf;
    float4 n0 = n4[0], n1 = n4[1], n2 = n4[2], n3 = n4[3];
    float4 w0 = s4[0], w1 = s4[1], w2 = s4[2], w3 = s4[3];
    float an = v0.x*n0.x + v0.y*n0.y + v0.z*n0.z + v0.w*n0.w
             + v1.x*n1.x + v1.y*n1.y + v1.z*n1.z + v1.w*n1.w
             + v2.x*n2.x + v2.y*n2.y + v2.z*n2.z + v2.w*n2.w
             + v3.x*n3.x + v3.y*n3.y + v3.z*n3.z + v3.w*n3.w;
    float as = v0.x*w0.x + v0.y*w0.y + v0.z*w0.z + v0.w*w0.w
             + v1.x*w1.x + v1.y*w1.y + v1.z*w1.z + v1.w*w1.w
             + v2.x*w2.x + v2.y*w2.y + v2.z*w2.z + v2.w*w2.w
             + v3.x*w3.x + v3.y*w3.y + v3.z*w3.z + v3.w*w3.w;
    a[i] = an;
    s[i] = as;
}

// ---------- binning phase 1: per-block histogram over dst bins ----------
__global__ __launch_bounds__(256) void hist_kernel(const int* __restrict__ dst, int E, int chunk,
                                                   u32* __restrict__ blockHist) {
    __shared__ u32 cnt[NBINS];
    for (int t = threadIdx.x; t < NBINS; t += 256) cnt[t] = 0;
    __syncthreads();
    int b = blockIdx.x;
    int lo = b * chunk, hi = min(lo + chunk, E);
    for (int i = lo + threadIdx.x; i < hi; i += 256)
        atomicAdd(&cnt[((u32)dst[i]) >> 10], 1u);
    __syncthreads();
    for (int t = threadIdx.x; t < NBINS; t += 256)
        blockHist[(size_t)b * NBINS + t] = cnt[t];
}

// ---------- binning phase 2a: per-bin exclusive scan over NBLK blocks ----------
__global__ __launch_bounds__(256) void scan1_kernel(u32* __restrict__ blockHist,
                                                    u32* __restrict__ binTotal) {
    int j = blockIdx.x;                       // bin
    __shared__ u32 lsum[256];
    int base = threadIdx.x * 4;               // NBLK = 256*4
    u32 v[4]; u32 ssum = 0;
    for (int k = 0; k < 4; ++k) { v[k] = blockHist[(size_t)(base + k) * NBINS + j]; ssum += v[k]; }
    lsum[threadIdx.x] = ssum;
    __syncthreads();
    u32 x = ssum;
    for (int off = 1; off < 256; off <<= 1) {
        u32 y = (threadIdx.x >= off) ? lsum[threadIdx.x - off] : 0u;
        __syncthreads();
        x += y; lsum[threadIdx.x] = x;
        __syncthreads();
    }
    u32 excl = x - ssum;
    if (threadIdx.x == 255) binTotal[j] = x;
    u32 run = excl;
    for (int k = 0; k < 4; ++k) { u32 old = v[k]; blockHist[(size_t)(base + k) * NBINS + j] = run; run += old; }
}

// ---------- binning phase 2b: exclusive scan over bin totals ----------
__global__ void scan2_kernel(const u32* __restrict__ binTotal, u32* __restrict__ binStart) {
    if (threadIdx.x == 0) {
        u32 run = 0;
        for (int j = 0; j < NBINS; ++j) { binStart[j] = run; run += binTotal[j]; }
        binStart[NBINS] = run;
    }
}

// ---------- binning phase 3: scatter edges into bin order ----------
__global__ __launch_bounds__(256) void scatter_kernel(const int* __restrict__ src,
                                                      const int* __restrict__ dst,
                                                      const float* __restrict__ ew,
                                                      int E, int chunk,
                                                      const u32* __restrict__ blockHist,
                                                      const u32* __restrict__ binStart,
                                                      uint2* __restrict__ binned) {
    __shared__ u32 pos[NBINS];
    int b = blockIdx.x;
    for (int t = threadIdx.x; t < NBINS; t += 256)
        pos[t] = binStart[t] + blockHist[(size_t)b * NBINS + t];
    __syncthreads();
    int lo = b * chunk, hi = min(lo + chunk, E);
    for (int i = lo + threadIdx.x; i < hi; i += 256) {
        u32 d = (u32)dst[i];
        u32 bin = d >> 10;
        u32 p = atomicAdd(&pos[bin], 1u);
        uint2 rec;
        rec.x = ((u32)src[i]) | ((d & 1023u) << 19);   // src < 2^19, dstLocal 10 bits
        rec.y = __float_as_uint(ew[i]);
        binned[p] = rec;
    }
}

// ---------- per-layer: gather + LDS-accumulate + fused node update ----------
__global__ __launch_bounds__(512) void bin_pass(const uint2* __restrict__ binned,
                                                const u32* __restrict__ binStart,
                                                const float* __restrict__ hsrc,
                                                const float* __restrict__ selfv,
                                                const float* __restrict__ wnp,  // scalar or nullptr (=1)
                                                const float* __restrict__ bp,   // scalar bias
                                                const float* __restrict__ wsp,  // scalar or nullptr (=1)
                                                float* __restrict__ hout) {
    __shared__ float acc[NPB];
    int j = blockIdx.x;
    for (int t = threadIdx.x; t < NPB; t += 512) acc[t] = 0.0f;
    __syncthreads();
    u32 lo = binStart[j], hi = binStart[j + 1];
    for (u32 i = lo + threadIdx.x; i < hi; i += 512) {
        uint2 e = binned[i];
        u32 sidx = e.x & 0x7FFFFu;
        u32 dl   = e.x >> 19;
        atomicAdd(&acc[dl], hsrc[sidx] * __uint_as_float(e.y));
    }
    __syncthreads();
    float scale = wnp ? wnp[0] : 1.0f;
    float bias  = bp[0];
    float wself = wsp ? wsp[0] : 1.0f;
    int base = j * NPB;
    for (int t = threadIdx.x; t < NPB; t += 512) {
        int node = base + t;
        if (node < N_NODES)
            hout[node] = fmaxf(acc[t] * scale + bias + selfv[node] * wself, 0.0f);
    }
}

// ---------- fallback path (global atomics) ----------
__global__ void edge_pass(const int* __restrict__ src, const int* __restrict__ dst,
                          const float* __restrict__ ew, const float* __restrict__ h,
                          float* __restrict__ agg, const float* __restrict__ wnp, int E) {
    float scale = wnp ? wnp[0] : 1.0f;
    int stride = gridDim.x * blockDim.x;
    for (int i = blockIdx.x * blockDim.x + threadIdx.x; i < E; i += stride)
        atomicAdd(&agg[dst[i]], h[src[i]] * ew[i] * scale);
}
__global__ void node_update(const float* __restrict__ agg, const float* __restrict__ selfv,
                            const float* __restrict__ bp, const float* __restrict__ wsp,
                            float* __restrict__ hout) {
    int i = blockIdx.x * blockDim.x + threadIdx.x;
    if (i >= N_NODES) return;
    float wsc = wsp ? wsp[0] : 1.0f;
    hout[i] = fmaxf(agg[i] + bp[0] + selfv[i] * wsc, 0.0f);
}

// ---------- per-graph sum (graph_id sorted) ----------
__global__ void graph_sum(const float* __restrict__ h, const int* __restrict__ gid,
                          float* __restrict__ hg) {
    __shared__ float loc[NGRAPH];
    int t = threadIdx.x;
    if (t < NGRAPH) loc[t] = 0.0f;
    __syncthreads();
    int stride = gridDim.x * blockDim.x;
    for (int i = blockIdx.x * blockDim.x + t; i < N_NODES; i += stride)
        atomicAdd(&loc[gid[i]], h[i]);
    __syncthreads();
    if (t < NGRAPH) atomicAdd(&hg[t], loc[t]);
}

// ---------- head MLP + log_softmax ----------
__global__ void head_kernel(const float* __restrict__ hg,
                            const float* __restrict__ fc1w, const float* __restrict__ fc1b,
                            const float* __restrict__ outw, const float* __restrict__ outb,
                            float* __restrict__ out) {
    int g = threadIdx.x;
    if (g >= NGRAPH) return;
    float v = hg[g];
    float t[8];
#pragma unroll
    for (int j = 0; j < 8; ++j) {
        float z = (v * fc1w[j] + fc1b[j]) * 1000.0f;
        t[j] = 1.0f / (1.0f + expf(-z));
    }
    float o[4];
#pragma unroll
    for (int k = 0; k < 4; ++k) {
        float acc2 = outb[k];
#pragma unroll
        for (int j = 0; j < 8; ++j) acc2 += t[j] * outw[k * 8 + j];
        o[k] = fmaxf(acc2, 0.0f);
    }
    float m = fmaxf(fmaxf(o[0], o[1]), fmaxf(o[2], o[3]));
    float se = 0.0f;
#pragma unroll
    for (int k = 0; k < 4; ++k) se += expf(o[k] - m);
    float lse = m + logf(se);
#pragma unroll
    for (int k = 0; k < 4; ++k) out[g * 4 + k] = o[k] - lse;
}

extern "C" void kernel_launch(void* const* d_in, const int* in_sizes, int n_in,
                              void* d_out, int out_size, void* d_ws, size_t ws_size,
                              hipStream_t stream) {
    const float* x    = (const float*)d_in[0];
    const int*   src  = (const int*)  d_in[1];
    const int*   dst  = (const int*)  d_in[2];
    const int*   gid  = (const int*)  d_in[3];
    const float* ew   = (const float*)d_in[4];
    const float* wn0  = (const float*)d_in[6];
    const float* b0   = (const float*)d_in[7];
    const float* ws0  = (const float*)d_in[8];
    const float* wn1  = (const float*)d_in[9];
    const float* b1   = (const float*)d_in[10];
    const float* ws1  = (const float*)d_in[11];
    const float* wn2  = (const float*)d_in[12];
    const float* b2   = (const float*)d_in[13];
    const float* ws2  = (const float*)d_in[14];
    const float* fc1w = (const float*)d_in[15];
    const float* fc1b = (const float*)d_in[16];
    const float* outw = (const float*)d_in[17];
    const float* outb = (const float*)d_in[18];
    int E = in_sizes[1];

    const int BLK = 256;
    int nodeGrid = (N_NODES + BLK - 1) / BLK;

    // workspace layout
    char* ws = (char*)d_ws;
    size_t need = (size_t)E * 8 + (size_t)NBLK * NBINS * 4 + (NBINS + 2) * 4 + 64
                + 4 * (size_t)N_NODES * 4 + NGRAPH * 4 + 256;

    if (ws_size >= need) {
        size_t off = 0;
        uint2* binned    = (uint2*)(ws + off); off += (size_t)E * 8;
        u32*   blockHist = (u32*)(ws + off);   off += (size_t)NBLK * NBINS * 4;
        u32*   binStart  = (u32*)(ws + off);   off += (NBINS + 1) * 4;
        off = (off + 15) & ~(size_t)15;
        u32*   binTotal  = (u32*)(ws + off);   off += (NBINS + 1) * 4;
        off = (off + 15) & ~(size_t)15;
        float* a  = (float*)(ws + off); off += (size_t)N_NODES * 4;
        float* s  = (float*)(ws + off); off += (size_t)N_NODES * 4;
        float* h0 = (float*)(ws + off); off += (size_t)N_NODES * 4;
        float* h1 = (float*)(ws + off); off += (size_t)N_NODES * 4;
        float* hg = (float*)(ws + off);

        int chunk = (E + NBLK - 1) / NBLK;

        proj_kernel<<<nodeGrid, BLK, 0, stream>>>(x, wn0, ws0, a, s);

        hist_kernel<<<NBLK, 256, 0, stream>>>(dst, E, chunk, blockHist);
        scan1_kernel<<<NBINS, 256, 0, stream>>>(blockHist, binTotal);
        scan2_kernel<<<1, 64, 0, stream>>>(binTotal, binStart);
        scatter_kernel<<<NBLK, 256, 0, stream>>>(src, dst, ew, E, chunk, blockHist, binStart, binned);

        bin_pass<<<NBINS, 512, 0, stream>>>(binned, binStart, a,  s,  nullptr, b0, nullptr, h0);
        bin_pass<<<NBINS, 512, 0, stream>>>(binned, binStart, h0, h0, wn1,     b1, ws1,     h1);
        bin_pass<<<NBINS, 512, 0, stream>>>(binned, binStart, h1, h1, wn2,     b2, ws2,     h0);

        hipMemsetAsync(hg, 0, NGRAPH * sizeof(float), stream);
        graph_sum<<<512, BLK, 0, stream>>>(h0, gid, hg);
        head_kernel<<<1, 64, 0, stream>>>(hg, fc1w, fc1b, outw, outb, (float*)d_out);
    } else {
        // fallback: global-atomic path (round-1 behavior)
        float* wsb = (float*)d_ws;
        float* a   = wsb;
        float* s   = wsb + 1 * (size_t)N_NODES;
        float* agg = wsb + 2 * (size_t)N_NODES;
        float* h   = wsb + 3 * (size_t)N_NODES;
        float* hg  = wsb + 4 * (size_t)N_NODES;

        proj_kernel<<<nodeGrid, BLK, 0, stream>>>(x, wn0, ws0, a, s);

        hipMemsetAsync(agg, 0, (size_t)N_NODES * sizeof(float), stream);
        edge_pass<<<4096, BLK, 0, stream>>>(src, dst, ew, a, agg, nullptr, E);
        node_update<<<nodeGrid, BLK, 0, stream>>>(agg, s, b0, nullptr, h);

        hipMemsetAsync(agg, 0, (size_t)N_NODES * sizeof(float), stream);
        edge_pass<<<4096, BLK, 0, stream>>>(src, dst, ew, h, agg, wn1, E);
        node_update<<<nodeGrid, BLK, 0, stream>>>(agg, h, b1, ws1, h);

        hipMemsetAsync(agg, 0, (size_t)N_NODES * sizeof(float), stream);
        edge_pass<<<4096, BLK, 0, stream>>>(src, dst, ew, h, agg, wn2, E);
        node_update<<<nodeGrid, BLK, 0, stream>>>(agg, h, b2, ws2, h);

        hipMemsetAsync(hg, 0, NGRAPH * sizeof(float), stream);
        graph_sum<<<512, BLK, 0, stream>>>(h, gid, hg);
        head_kernel<<<1, 64, 0, stream>>>(hg, fc1w, fc1b, outw, outb, (float*)d_out);
    }
}

// Round 3
// 599.008 us; speedup vs baseline: 3.9781x; 1.2060x over previous
//
#include <hip/hip_runtime.h>

#define N_NODES 500000
#define NGRAPH  64
#define FDIM    16
#define NPB     1024                 // nodes per bin (power of 2)
#define NBINS   489                  // ceil(N_NODES / NPB)
#define NBLK    256                  // binning blocks (few blocks => few concurrent write streams)
typedef unsigned int u32;

// ---------- per-node projections: a = x.w_neigh0, s = x.w_self0 ----------
__global__ void proj_kernel(const float* __restrict__ x,
                            const float* __restrict__ wn,   // [16]
                            const float* __restrict__ wsf,  // [16]
                            float* __restrict__ a,
                            float* __restrict__ s) {
    int i = blockIdx.x * blockDim.x + threadIdx.x;
    if (i >= N_NODES) return;
    const float4* xr = (const float4*)(x + (size_t)i * FDIM);
    float4 v0 = xr[0], v1 = xr[1], v2 = xr[2], v3 = xr[3];
    const float4* n4 = (const float4*)wn;
    const float4* s4 = (const float4*)wsf;
    float4 n0 = n4[0], n1 = n4[1], n2 = n4[2], n3 = n4[3];
    float4 w0 = s4[0], w1 = s4[1], w2 = s4[2], w3 = s4[3];
    float an = v0.x*n0.x + v0.y*n0.y + v0.z*n0.z + v0.w*n0.w
             + v1.x*n1.x + v1.y*n1.y + v1.z*n1.z + v1.w*n1.w
             + v2.x*n2.x + v2.y*n2.y + v2.z*n2.z + v2.w*n2.w
             + v3.x*n3.x + v3.y*n3.y + v3.z*n3.z + v3.w*n3.w;
    float as = v0.x*w0.x + v0.y*w0.y + v0.z*w0.z + v0.w*w0.w
             + v1.x*w1.x + v1.y*w1.y + v1.z*w1.z + v1.w*w1.w
             + v2.x*w2.x + v2.y*w2.y + v2.z*w2.z + v2.w*w2.w
             + v3.x*w3.x + v3.y*w3.y + v3.z*w3.z + v3.w*w3.w;
    a[i] = an;
    s[i] = as;
}

// ---------- binning phase 1: per-block histogram over dst bins ----------
__global__ __launch_bounds__(512) void hist_kernel(const int* __restrict__ dst, int E, int chunk,
                                                   u32* __restrict__ blockHist) {
    __shared__ u32 cnt[NBINS];
    for (int t = threadIdx.x; t < NBINS; t += 512) cnt[t] = 0;
    __syncthreads();
    int b = blockIdx.x;
    int lo = b * chunk, hi = min(lo + chunk, E);
    for (int i = lo + threadIdx.x; i < hi; i += 512)
        atomicAdd(&cnt[((u32)dst[i]) >> 10], 1u);
    __syncthreads();
    for (int t = threadIdx.x; t < NBINS; t += 512)
        blockHist[(size_t)b * NBINS + t] = cnt[t];
}

// ---------- binning phase 2a: per-bin exclusive scan over NBLK blocks ----------
__global__ __launch_bounds__(NBLK) void scan1_kernel(u32* __restrict__ blockHist,
                                                     u32* __restrict__ binTotal) {
    int j = blockIdx.x;                       // bin
    __shared__ u32 lsum[NBLK];
    int t = threadIdx.x;
    u32 v = blockHist[(size_t)t * NBINS + j];
    lsum[t] = v;
    __syncthreads();
    u32 x = v;
    for (int off = 1; off < NBLK; off <<= 1) {
        u32 y = (t >= off) ? lsum[t - off] : 0u;
        __syncthreads();
        x += y; lsum[t] = x;
        __syncthreads();
    }
    if (t == NBLK - 1) binTotal[j] = x;
    blockHist[(size_t)t * NBINS + j] = x - v;   // exclusive
}

// ---------- binning phase 2b: exclusive scan over bin totals ----------
__global__ void scan2_kernel(const u32* __restrict__ binTotal, u32* __restrict__ binStart) {
    if (threadIdx.x == 0) {
        u32 run = 0;
        for (int j = 0; j < NBINS; ++j) { binStart[j] = run; run += binTotal[j]; }
        binStart[NBINS] = run;
    }
}

// ---------- binning phase 3: scatter edges into bin order ----------
__global__ __launch_bounds__(512) void scatter_kernel(const int* __restrict__ src,
                                                      const int* __restrict__ dst,
                                                      const float* __restrict__ ew,
                                                      int E, int chunk,
                                                      const u32* __restrict__ blockHist,
                                                      const u32* __restrict__ binStart,
                                                      uint2* __restrict__ binned) {
    __shared__ u32 pos[NBINS];
    int b = blockIdx.x;
    for (int t = threadIdx.x; t < NBINS; t += 512)
        pos[t] = binStart[t] + blockHist[(size_t)b * NBINS + t];
    __syncthreads();
    int lo = b * chunk, hi = min(lo + chunk, E);
    for (int i = lo + threadIdx.x; i < hi; i += 512) {
        u32 d = (u32)dst[i];
        u32 bin = d >> 10;
        u32 p = atomicAdd(&pos[bin], 1u);
        uint2 rec;
        rec.x = ((u32)src[i]) | ((d & 1023u) << 19);   // src < 2^19, dstLocal 10 bits
        rec.y = __float_as_uint(ew[i]);
        binned[p] = rec;
    }
}

// ---------- per-layer: gather + LDS-accumulate + fused node update ----------
__global__ __launch_bounds__(512) void bin_pass(const uint2* __restrict__ binned,
                                                const u32* __restrict__ binStart,
                                                const float* __restrict__ hsrc,
                                                const float* __restrict__ selfv,
                                                const float* __restrict__ wnp,  // scalar or nullptr (=1)
                                                const float* __restrict__ bp,   // scalar bias
                                                const float* __restrict__ wsp,  // scalar or nullptr (=1)
                                                float* __restrict__ hout) {
    __shared__ float acc[NPB];
    int j = blockIdx.x;
    for (int t = threadIdx.x; t < NPB; t += 512) acc[t] = 0.0f;
    __syncthreads();
    u32 lo = binStart[j], hi = binStart[j + 1];
    for (u32 i = lo + threadIdx.x; i < hi; i += 512) {
        uint2 e = binned[i];
        u32 sidx = e.x & 0x7FFFFu;
        u32 dl   = e.x >> 19;
        atomicAdd(&acc[dl], hsrc[sidx] * __uint_as_float(e.y));
    }
    __syncthreads();
    float scale = wnp ? wnp[0] : 1.0f;
    float bias  = bp[0];
    float wself = wsp ? wsp[0] : 1.0f;
    int base = j * NPB;
    for (int t = threadIdx.x; t < NPB; t += 512) {
        int node = base + t;
        if (node < N_NODES)
            hout[node] = fmaxf(acc[t] * scale + bias + selfv[node] * wself, 0.0f);
    }
}

// ---------- per-graph sum (graph_id sorted) ----------
__global__ void graph_sum(const float* __restrict__ h, const int* __restrict__ gid,
                          float* __restrict__ hg) {
    __shared__ float loc[NGRAPH];
    int t = threadIdx.x;
    if (t < NGRAPH) loc[t] = 0.0f;
    __syncthreads();
    int stride = gridDim.x * blockDim.x;
    for (int i = blockIdx.x * blockDim.x + t; i < N_NODES; i += stride)
        atomicAdd(&loc[gid[i]], h[i]);
    __syncthreads();
    if (t < NGRAPH) atomicAdd(&hg[t], loc[t]);
}

// ---------- head MLP + log_softmax ----------
__global__ void head_kernel(const float* __restrict__ hg,
                            const float* __restrict__ fc1w, const float* __restrict__ fc1b,
                            const float* __restrict__ outw, const float* __restrict__ outb,
                            float* __restrict__ out) {
    int g = threadIdx.x;
    if (g >= NGRAPH) return;
    float v = hg[g];
    float t[8];
#pragma unroll
    for (int j = 0; j < 8; ++j) {
        float z = (v * fc1w[j] + fc1b[j]) * 1000.0f;
        t[j] = 1.0f / (1.0f + expf(-z));
    }
    float o[4];
#pragma unroll
    for (int k = 0; k < 4; ++k) {
        float acc2 = outb[k];
#pragma unroll
        for (int j = 0; j < 8; ++j) acc2 += t[j] * outw[k * 8 + j];
        o[k] = fmaxf(acc2, 0.0f);
    }
    float m = fmaxf(fmaxf(o[0], o[1]), fmaxf(o[2], o[3]));
    float se = 0.0f;
#pragma unroll
    for (int k = 0; k < 4; ++k) se += expf(o[k] - m);
    float lse = m + logf(se);
#pragma unroll
    for (int k = 0; k < 4; ++k) out[g * 4 + k] = o[k] - lse;
}

extern "C" void kernel_launch(void* const* d_in, const int* in_sizes, int n_in,
                              void* d_out, int out_size, void* d_ws, size_t ws_size,
                              hipStream_t stream) {
    const float* x    = (const float*)d_in[0];
    const int*   src  = (const int*)  d_in[1];
    const int*   dst  = (const int*)  d_in[2];
    const int*   gid  = (const int*)  d_in[3];
    const float* ew   = (const float*)d_in[4];
    const float* wn0  = (const float*)d_in[6];
    const float* b0   = (const float*)d_in[7];
    const float* ws0  = (const float*)d_in[8];
    const float* wn1  = (const float*)d_in[9];
    const float* b1   = (const float*)d_in[10];
    const float* ws1  = (const float*)d_in[11];
    const float* wn2  = (const float*)d_in[12];
    const float* b2   = (const float*)d_in[13];
    const float* ws2  = (const float*)d_in[14];
    const float* fc1w = (const float*)d_in[15];
    const float* fc1b = (const float*)d_in[16];
    const float* outw = (const float*)d_in[17];
    const float* outb = (const float*)d_in[18];
    int E = in_sizes[1];

    const int BLK = 256;
    int nodeGrid = (N_NODES + BLK - 1) / BLK;

    char* ws = (char*)d_ws;
    size_t need = (size_t)E * 8 + (size_t)NBLK * NBINS * 4 + (NBINS + 2) * 4 + 64
                + 4 * (size_t)N_NODES * 4 + NGRAPH * 4 + 256;

    if (ws_size >= need) {
        size_t off = 0;
        uint2* binned    = (uint2*)(ws + off); off += (size_t)E * 8;
        u32*   blockHist = (u32*)(ws + off);   off += (size_t)NBLK * NBINS * 4;
        u32*   binStart  = (u32*)(ws + off);   off += (NBINS + 1) * 4;
        off = (off + 15) & ~(size_t)15;
        u32*   binTotal  = (u32*)(ws + off);   off += (NBINS + 1) * 4;
        off = (off + 15) & ~(size_t)15;
        float* a  = (float*)(ws + off); off += (size_t)N_NODES * 4;
        float* s  = (float*)(ws + off); off += (size_t)N_NODES * 4;
        float* h0 = (float*)(ws + off); off += (size_t)N_NODES * 4;
        float* h1 = (float*)(ws + off); off += (size_t)N_NODES * 4;
        float* hg = (float*)(ws + off);

        int chunk = (E + NBLK - 1) / NBLK;

        proj_kernel<<<nodeGrid, BLK, 0, stream>>>(x, wn0, ws0, a, s);

        hist_kernel<<<NBLK, 512, 0, stream>>>(dst, E, chunk, blockHist);
        scan1_kernel<<<NBINS, NBLK, 0, stream>>>(blockHist, binTotal);
        scan2_kernel<<<1, 64, 0, stream>>>(binTotal, binStart);
        scatter_kernel<<<NBLK, 512, 0, stream>>>(src, dst, ew, E, chunk, blockHist, binStart, binned);

        bin_pass<<<NBINS, 512, 0, stream>>>(binned, binStart, a,  s,  nullptr, b0, nullptr, h0);
        bin_pass<<<NBINS, 512, 0, stream>>>(binned, binStart, h0, h0, wn1,     b1, ws1,     h1);
        bin_pass<<<NBINS, 512, 0, stream>>>(binned, binStart, h1, h1, wn2,     b2, ws2,     h0);

        hipMemsetAsync(hg, 0, NGRAPH * sizeof(float), stream);
        graph_sum<<<512, BLK, 0, stream>>>(h0, gid, hg);
        head_kernel<<<1, 64, 0, stream>>>(hg, fc1w, fc1b, outw, outb, (float*)d_out);
    } else {
        // fallback: should not trigger (ws is sized by harness); minimal atomic path
        float* wsb = (float*)d_ws;
        float* a   = wsb;
        float* s   = wsb + 1 * (size_t)N_NODES;
        float* hg  = wsb + 2 * (size_t)N_NODES;
        proj_kernel<<<nodeGrid, BLK, 0, stream>>>(x, wn0, ws0, a, s);
        hipMemsetAsync(hg, 0, NGRAPH * sizeof(float), stream);
        graph_sum<<<512, BLK, 0, stream>>>(a, gid, hg);
        head_kernel<<<1, 64, 0, stream>>>(hg, fc1w, fc1b, outw, outb, (float*)d_out);
    }
}

// Round 5
// 485.169 us; speedup vs baseline: 4.9116x; 1.2346x over previous
//
#include <hip/hip_runtime.h>

#define N_NODES   500000
#define NGRAPH    64
#define FDIM      16
#define NPB       4096               // nodes per bin
#define NPB_SHIFT 12
#define NBINS     123                // ceil(500000/4096)
#define SLICES    4                  // edge slices per bin in bin_pass
#define NBLK      256                // binning blocks
typedef unsigned int u32;
typedef unsigned long long u64;

// ---------- per-node projections: a = x.w_neigh0, s = x.w_self0 ----------
__global__ void proj_kernel(const float* __restrict__ x,
                            const float* __restrict__ wn,
                            const float* __restrict__ wsf,
                            float* __restrict__ a,
                            float* __restrict__ s) {
    int i = blockIdx.x * blockDim.x + threadIdx.x;
    if (i >= N_NODES) return;
    const float4* xr = (const float4*)(x + (size_t)i * FDIM);
    float4 v0 = xr[0], v1 = xr[1], v2 = xr[2], v3 = xr[3];
    const float4* n4 = (const float4*)wn;
    const float4* s4 = (const float4*)wsf;
    float4 n0 = n4[0], n1 = n4[1], n2 = n4[2], n3 = n4[3];
    float4 w0 = s4[0], w1 = s4[1], w2 = s4[2], w3 = s4[3];
    float an = v0.x*n0.x + v0.y*n0.y + v0.z*n0.z + v0.w*n0.w
             + v1.x*n1.x + v1.y*n1.y + v1.z*n1.z + v1.w*n1.w
             + v2.x*n2.x + v2.y*n2.y + v2.z*n2.z + v2.w*n2.w
             + v3.x*n3.x + v3.y*n3.y + v3.z*n3.z + v3.w*n3.w;
    float as = v0.x*w0.x + v0.y*w0.y + v0.z*w0.z + v0.w*w0.w
             + v1.x*w1.x + v1.y*w1.y + v1.z*w1.z + v1.w*w1.w
             + v2.x*w2.x + v2.y*w2.y + v2.z*w2.z + v2.w*w2.w
             + v3.x*w3.x + v3.y*w3.y + v3.z*w3.z + v3.w*w3.w;
    a[i] = an;
    s[i] = as;
}

// ---------- binning phase 1: per-block histogram over dst bins ----------
__global__ __launch_bounds__(1024) void hist_kernel(const int* __restrict__ dst, int E, int chunk,
                                                    u32* __restrict__ blockHist) {
    __shared__ u32 cnt[NBINS];
    for (int t = threadIdx.x; t < NBINS; t += 1024) cnt[t] = 0;
    __syncthreads();
    int b = blockIdx.x;
    int lo = b * chunk, hi = min(lo + chunk, E);
    int m = (hi - lo) & ~3;
    for (int i = lo + threadIdx.x * 4; i < lo + m; i += 4096) {
        int4 d = *(const int4*)(dst + i);
        atomicAdd(&cnt[((u32)d.x) >> NPB_SHIFT], 1u);
        atomicAdd(&cnt[((u32)d.y) >> NPB_SHIFT], 1u);
        atomicAdd(&cnt[((u32)d.z) >> NPB_SHIFT], 1u);
        atomicAdd(&cnt[((u32)d.w) >> NPB_SHIFT], 1u);
    }
    for (int i = lo + m + threadIdx.x; i < hi; i += 1024)
        atomicAdd(&cnt[((u32)dst[i]) >> NPB_SHIFT], 1u);
    __syncthreads();
    for (int t = threadIdx.x; t < NBINS; t += 1024)
        blockHist[(size_t)b * NBINS + t] = cnt[t];
}

// ---------- binning phase 2a: per-bin exclusive scan over NBLK blocks ----------
__global__ __launch_bounds__(NBLK) void scan1_kernel(u32* __restrict__ blockHist,
                                                     u32* __restrict__ binTotal) {
    int j = blockIdx.x;                       // bin
    __shared__ u32 lsum[NBLK];
    int t = threadIdx.x;
    u32 v = blockHist[(size_t)t * NBINS + j];
    lsum[t] = v;
    __syncthreads();
    u32 x = v;
    for (int off = 1; off < NBLK; off <<= 1) {
        u32 y = (t >= off) ? lsum[t - off] : 0u;
        __syncthreads();
        x += y; lsum[t] = x;
        __syncthreads();
    }
    if (t == NBLK - 1) binTotal[j] = x;
    blockHist[(size_t)t * NBINS + j] = x - v;   // exclusive prefix within bin
}

// ---------- binning phase 2b: exclusive scan over bin totals ----------
__global__ void scan2_kernel(const u32* __restrict__ binTotal, u32* __restrict__ binStart) {
    if (threadIdx.x == 0) {
        u32 run = 0;
        for (int j = 0; j < NBINS; ++j) { binStart[j] = run; run += binTotal[j]; }
        binStart[NBINS] = run;
    }
}

// ---------- binning phase 3: scatter edges into bin order ----------
__global__ __launch_bounds__(1024) void scatter_kernel(const int* __restrict__ src,
                                                       const int* __restrict__ dst,
                                                       const float* __restrict__ ew,
                                                       int E, int chunk,
                                                       const u32* __restrict__ blockHist,
                                                       const u32* __restrict__ binStart,
                                                       u64* __restrict__ binned) {
    __shared__ u32 pos[NBINS];
    int b = blockIdx.x;
    for (int t = threadIdx.x; t < NBINS; t += 1024)
        pos[t] = binStart[t] + blockHist[(size_t)b * NBINS + t];
    __syncthreads();
    int lo = b * chunk, hi = min(lo + chunk, E);
    int m = (hi - lo) & ~3;
    for (int i = lo + threadIdx.x * 4; i < lo + m; i += 4096) {
        int4   ss = *(const int4*)(src + i);
        int4   dd = *(const int4*)(dst + i);
        float4 ww = *(const float4*)(ew + i);
        u32 d0 = (u32)dd.x, d1 = (u32)dd.y, d2 = (u32)dd.z, d3 = (u32)dd.w;
        u32 p0 = atomicAdd(&pos[d0 >> NPB_SHIFT], 1u);
        u32 p1 = atomicAdd(&pos[d1 >> NPB_SHIFT], 1u);
        u32 p2 = atomicAdd(&pos[d2 >> NPB_SHIFT], 1u);
        u32 p3 = atomicAdd(&pos[d3 >> NPB_SHIFT], 1u);
        u32 r0 = ((u32)ss.x) | ((d0 & (NPB-1)) << 19);
        u32 r1 = ((u32)ss.y) | ((d1 & (NPB-1)) << 19);
        u32 r2 = ((u32)ss.z) | ((d2 & (NPB-1)) << 19);
        u32 r3 = ((u32)ss.w) | ((d3 & (NPB-1)) << 19);
        binned[p0] = (u64)r0 | ((u64)__float_as_uint(ww.x) << 32);
        binned[p1] = (u64)r1 | ((u64)__float_as_uint(ww.y) << 32);
        binned[p2] = (u64)r2 | ((u64)__float_as_uint(ww.z) << 32);
        binned[p3] = (u64)r3 | ((u64)__float_as_uint(ww.w) << 32);
    }
    for (int i = lo + m + threadIdx.x; i < hi; i += 1024) {
        u32 d = (u32)dst[i];
        u32 p = atomicAdd(&pos[d >> NPB_SHIFT], 1u);
        binned[p] = (u64)(((u32)src[i]) | ((d & (NPB-1)) << 19))
                  | ((u64)__float_as_uint(ew[i]) << 32);
    }
}

// ---------- per-layer: gather + LDS-accumulate into per-slice partials ----------
__global__ __launch_bounds__(512) void bin_pass(const u64* __restrict__ binned,
                                                const u32* __restrict__ binStart,
                                                const float* __restrict__ hsrc,
                                                float* __restrict__ partials) {
    __shared__ float acc[NPB];
    int blk   = blockIdx.x;
    int j     = blk >> 2;            // bin
    int slice = blk & (SLICES - 1);
    for (int t = threadIdx.x; t < NPB; t += 512) acc[t] = 0.0f;
    __syncthreads();
    u32 blo = binStart[j], bhi = binStart[j + 1];
    u32 cnt = bhi - blo;
    u32 per = (cnt + SLICES - 1) / SLICES;
    u32 lo = blo + slice * per;
    u32 hi = min(lo + per, bhi);

    u32 i = lo + threadIdx.x;
    // 4-way unrolled: 4 independent record loads -> 4 gathers -> 4 LDS atomics
    for (; i + 3u * 512u < hi; i += 4u * 512u) {
        u64 e0 = __builtin_nontemporal_load(&binned[i]);
        u64 e1 = __builtin_nontemporal_load(&binned[i + 512]);
        u64 e2 = __builtin_nontemporal_load(&binned[i + 1024]);
        u64 e3 = __builtin_nontemporal_load(&binned[i + 1536]);
        u32 x0 = (u32)e0, x1 = (u32)e1, x2 = (u32)e2, x3 = (u32)e3;
        float g0 = hsrc[x0 & 0x7FFFFu];
        float g1 = hsrc[x1 & 0x7FFFFu];
        float g2 = hsrc[x2 & 0x7FFFFu];
        float g3 = hsrc[x3 & 0x7FFFFu];
        atomicAdd(&acc[x0 >> 19], g0 * __uint_as_float((u32)(e0 >> 32)));
        atomicAdd(&acc[x1 >> 19], g1 * __uint_as_float((u32)(e1 >> 32)));
        atomicAdd(&acc[x2 >> 19], g2 * __uint_as_float((u32)(e2 >> 32)));
        atomicAdd(&acc[x3 >> 19], g3 * __uint_as_float((u32)(e3 >> 32)));
    }
    for (; i < hi; i += 512) {
        u64 e = __builtin_nontemporal_load(&binned[i]);
        u32 xx = (u32)e;
        atomicAdd(&acc[xx >> 19], hsrc[xx & 0x7FFFFu] * __uint_as_float((u32)(e >> 32)));
    }
    __syncthreads();
    float* p = partials + (size_t)(j * SLICES + slice) * NPB;
    for (int t = threadIdx.x; t < NPB; t += 512)
        __builtin_nontemporal_store(acc[t], &p[t]);
}

// ---------- merge slices + bias + self-loop + relu ----------
__global__ void merge_update(const float* __restrict__ partials,
                             const float* __restrict__ selfv,
                             const float* __restrict__ wnp,  // scalar or nullptr (=1)
                             const float* __restrict__ bp,   // scalar bias
                             const float* __restrict__ wsp,  // scalar or nullptr (=1)
                             float* __restrict__ hout) {
    int n = blockIdx.x * blockDim.x + threadIdx.x;
    if (n >= N_NODES) return;
    int j = n >> NPB_SHIFT;
    int l = n & (NPB - 1);
    const float* p = partials + (size_t)j * SLICES * NPB + l;
    float sum = p[0] + p[NPB] + p[2 * NPB] + p[3 * NPB];
    float scale = wnp ? wnp[0] : 1.0f;
    float wself = wsp ? wsp[0] : 1.0f;
    hout[n] = fmaxf(sum * scale + bp[0] + selfv[n] * wself, 0.0f);
}

// ---------- fallback (global atomics), correct but slow ----------
__global__ void edge_pass(const int* __restrict__ src, const int* __restrict__ dst,
                          const float* __restrict__ ew, const float* __restrict__ h,
                          float* __restrict__ agg, const float* __restrict__ wnp, int E) {
    float scale = wnp ? wnp[0] : 1.0f;
    int stride = gridDim.x * blockDim.x;
    for (int i = blockIdx.x * blockDim.x + threadIdx.x; i < E; i += stride)
        atomicAdd(&agg[dst[i]], h[src[i]] * ew[i] * scale);
}
__global__ void node_update(const float* __restrict__ agg, const float* __restrict__ selfv,
                            const float* __restrict__ bp, const float* __restrict__ wsp,
                            float* __restrict__ hout) {
    int i = blockIdx.x * blockDim.x + threadIdx.x;
    if (i >= N_NODES) return;
    float wsc = wsp ? wsp[0] : 1.0f;
    hout[i] = fmaxf(agg[i] + bp[0] + selfv[i] * wsc, 0.0f);
}

// ---------- per-graph sum (graph_id sorted) ----------
__global__ void graph_sum(const float* __restrict__ h, const int* __restrict__ gid,
                          float* __restrict__ hg) {
    __shared__ float loc[NGRAPH];
    int t = threadIdx.x;
    if (t < NGRAPH) loc[t] = 0.0f;
    __syncthreads();
    int stride = gridDim.x * blockDim.x;
    for (int i = blockIdx.x * blockDim.x + t; i < N_NODES; i += stride)
        atomicAdd(&loc[gid[i]], h[i]);
    __syncthreads();
    if (t < NGRAPH) atomicAdd(&hg[t], loc[t]);
}

// ---------- head MLP + log_softmax ----------
__global__ void head_kernel(const float* __restrict__ hg,
                            const float* __restrict__ fc1w, const float* __restrict__ fc1b,
                            const float* __restrict__ outw, const float* __restrict__ outb,
                            float* __restrict__ out) {
    int g = threadIdx.x;
    if (g >= NGRAPH) return;
    float v = hg[g];
    float t[8];
#pragma unroll
    for (int j = 0; j < 8; ++j) {
        float z = (v * fc1w[j] + fc1b[j]) * 1000.0f;
        t[j] = 1.0f / (1.0f + expf(-z));
    }
    float o[4];
#pragma unroll
    for (int k = 0; k < 4; ++k) {
        float acc2 = outb[k];
#pragma unroll
        for (int j = 0; j < 8; ++j) acc2 += t[j] * outw[k * 8 + j];
        o[k] = fmaxf(acc2, 0.0f);
    }
    float m = fmaxf(fmaxf(o[0], o[1]), fmaxf(o[2], o[3]));
    float se = 0.0f;
#pragma unroll
    for (int k = 0; k < 4; ++k) se += expf(o[k] - m);
    float lse = m + logf(se);
#pragma unroll
    for (int k = 0; k < 4; ++k) out[g * 4 + k] = o[k] - lse;
}

extern "C" void kernel_launch(void* const* d_in, const int* in_sizes, int n_in,
                              void* d_out, int out_size, void* d_ws, size_t ws_size,
                              hipStream_t stream) {
    const float* x    = (const float*)d_in[0];
    const int*   src  = (const int*)  d_in[1];
    const int*   dst  = (const int*)  d_in[2];
    const int*   gid  = (const int*)  d_in[3];
    const float* ew   = (const float*)d_in[4];
    const float* wn0  = (const float*)d_in[6];
    const float* b0   = (const float*)d_in[7];
    const float* ws0  = (const float*)d_in[8];
    const float* wn1  = (const float*)d_in[9];
    const float* b1   = (const float*)d_in[10];
    const float* ws1  = (const float*)d_in[11];
    const float* wn2  = (const float*)d_in[12];
    const float* b2   = (const float*)d_in[13];
    const float* ws2  = (const float*)d_in[14];
    const float* fc1w = (const float*)d_in[15];
    const float* fc1b = (const float*)d_in[16];
    const float* outw = (const float*)d_in[17];
    const float* outb = (const float*)d_in[18];
    int E = in_sizes[1];

    const int BLK = 256;
    int nodeGrid = (N_NODES + BLK - 1) / BLK;
    char* ws = (char*)d_ws;

    // workspace layout
    size_t off = 0;
    u64*   binned    = (u64*)(ws + off);   off += (size_t)E * 8;
    u32*   blockHist = (u32*)(ws + off);   off += (size_t)NBLK * NBINS * 4;
    u32*   binStart  = (u32*)(ws + off);   off += (NBINS + 1) * 4;
    off = (off + 63) & ~(size_t)63;
    u32*   binTotal  = (u32*)(ws + off);   off += (NBINS + 1) * 4;
    off = (off + 63) & ~(size_t)63;
    float* partials  = (float*)(ws + off); off += (size_t)NBINS * SLICES * NPB * 4;
    float* a  = (float*)(ws + off); off += (size_t)N_NODES * 4;
    float* s  = (float*)(ws + off); off += (size_t)N_NODES * 4;
    float* h0 = (float*)(ws + off); off += (size_t)N_NODES * 4;
    float* h1 = (float*)(ws + off); off += (size_t)N_NODES * 4;
    float* hg = (float*)(ws + off); off += NGRAPH * 4;
    size_t need = off;

    if (ws_size >= need) {
        int chunk = (((E + NBLK - 1) / NBLK) + 3) & ~3;

        proj_kernel<<<nodeGrid, BLK, 0, stream>>>(x, wn0, ws0, a, s);

        hist_kernel<<<NBLK, 1024, 0, stream>>>(dst, E, chunk, blockHist);
        scan1_kernel<<<NBINS, NBLK, 0, stream>>>(blockHist, binTotal);
        scan2_kernel<<<1, 64, 0, stream>>>(binTotal, binStart);
        scatter_kernel<<<NBLK, 1024, 0, stream>>>(src, dst, ew, E, chunk, blockHist, binStart, binned);

        // layer 0
        bin_pass<<<NBINS * SLICES, 512, 0, stream>>>(binned, binStart, a, partials);
        merge_update<<<nodeGrid, BLK, 0, stream>>>(partials, s, nullptr, b0, nullptr, h0);
        // layer 1
        bin_pass<<<NBINS * SLICES, 512, 0, stream>>>(binned, binStart, h0, partials);
        merge_update<<<nodeGrid, BLK, 0, stream>>>(partials, h0, wn1, b1, ws1, h1);
        // layer 2 (output reuses a)
        bin_pass<<<NBINS * SLICES, 512, 0, stream>>>(binned, binStart, h1, partials);
        merge_update<<<nodeGrid, BLK, 0, stream>>>(partials, h1, wn2, b2, ws2, a);

        (void)hipMemsetAsync(hg, 0, NGRAPH * sizeof(float), stream);
        graph_sum<<<512, BLK, 0, stream>>>(a, gid, hg);
        head_kernel<<<1, 64, 0, stream>>>(hg, fc1w, fc1b, outw, outb, (float*)d_out);
    } else {
        // correct fallback: global-atomic path
        float* wsb  = (float*)d_ws;
        float* fa   = wsb;
        float* fs   = wsb + 1 * (size_t)N_NODES;
        float* fagg = wsb + 2 * (size_t)N_NODES;
        float* fh   = wsb + 3 * (size_t)N_NODES;
        float* fhg  = wsb + 4 * (size_t)N_NODES;

        proj_kernel<<<nodeGrid, BLK, 0, stream>>>(x, wn0, ws0, fa, fs);

        (void)hipMemsetAsync(fagg, 0, (size_t)N_NODES * sizeof(float), stream);
        edge_pass<<<4096, BLK, 0, stream>>>(src, dst, ew, fa, fagg, nullptr, E);
        node_update<<<nodeGrid, BLK, 0, stream>>>(fagg, fs, b0, nullptr, fh);

        (void)hipMemsetAsync(fagg, 0, (size_t)N_NODES * sizeof(float), stream);
        edge_pass<<<4096, BLK, 0, stream>>>(src, dst, ew, fh, fagg, wn1, E);
        node_update<<<nodeGrid, BLK, 0, stream>>>(fagg, fh, b1, ws1, fh);

        (void)hipMemsetAsync(fagg, 0, (size_t)N_NODES * sizeof(float), stream);
        edge_pass<<<4096, BLK, 0, stream>>>(src, dst, ew, fh, fagg, wn2, E);
        node_update<<<nodeGrid, BLK, 0, stream>>>(fagg, fh, b2, ws2, fh);

        (void)hipMemsetAsync(fhg, 0, NGRAPH * sizeof(float), stream);
        graph_sum<<<512, BLK, 0, stream>>>(fh, gid, fhg);
        head_kernel<<<1, 64, 0, stream>>>(fhg, fc1w, fc1b, outw, outb, (float*)d_out);
    }
}

// Round 6
// 424.169 us; speedup vs baseline: 5.6179x; 1.1438x over previous
//
#include <hip/hip_runtime.h>

#define N_NODES   500000
#define NGRAPH    64
#define FDIM      16
#define NPB       4096               // nodes per bin
#define NPB_SHIFT 12
#define NBINS     123                // ceil(500000/4096)
#define SLICES    4                  // edge slices per bin in bin_pass
#define NBLK      512                // binning blocks
#define CH        4096               // staged-scatter chunk (edges)
typedef unsigned int u32;
typedef unsigned long long u64;

// ---------- per-node projections: a = x.w_neigh0, s = x.w_self0 ----------
__global__ void proj_kernel(const float* __restrict__ x,
                            const float* __restrict__ wn,
                            const float* __restrict__ wsf,
                            float* __restrict__ a,
                            float* __restrict__ s) {
    int i = blockIdx.x * blockDim.x + threadIdx.x;
    if (i >= N_NODES) return;
    const float4* xr = (const float4*)(x + (size_t)i * FDIM);
    float4 v0 = xr[0], v1 = xr[1], v2 = xr[2], v3 = xr[3];
    const float4* n4 = (const float4*)wn;
    const float4* s4 = (const float4*)wsf;
    float4 n0 = n4[0], n1 = n4[1], n2 = n4[2], n3 = n4[3];
    float4 w0 = s4[0], w1 = s4[1], w2 = s4[2], w3 = s4[3];
    float an = v0.x*n0.x + v0.y*n0.y + v0.z*n0.z + v0.w*n0.w
             + v1.x*n1.x + v1.y*n1.y + v1.z*n1.z + v1.w*n1.w
             + v2.x*n2.x + v2.y*n2.y + v2.z*n2.z + v2.w*n2.w
             + v3.x*n3.x + v3.y*n3.y + v3.z*n3.z + v3.w*n3.w;
    float as = v0.x*w0.x + v0.y*w0.y + v0.z*w0.z + v0.w*w0.w
             + v1.x*w1.x + v1.y*w1.y + v1.z*w1.z + v1.w*w1.w
             + v2.x*w2.x + v2.y*w2.y + v2.z*w2.z + v2.w*w2.w
             + v3.x*w3.x + v3.y*w3.y + v3.z*w3.z + v3.w*w3.w;
    a[i] = an;
    s[i] = as;
}

// ---------- binning phase 1: per-block histogram over dst bins ----------
__global__ __launch_bounds__(1024) void hist_kernel(const int* __restrict__ dst, int E, int chunk,
                                                    u32* __restrict__ blockHist) {
    __shared__ u32 cnt[NBINS];
    for (int t = threadIdx.x; t < NBINS; t += 1024) cnt[t] = 0;
    __syncthreads();
    int b = blockIdx.x;
    int lo = b * chunk, hi = min(lo + chunk, E);
    int m = (hi - lo) & ~3;
    for (int i = lo + threadIdx.x * 4; i < lo + m; i += 4096) {
        int4 d = *(const int4*)(dst + i);
        atomicAdd(&cnt[((u32)d.x) >> NPB_SHIFT], 1u);
        atomicAdd(&cnt[((u32)d.y) >> NPB_SHIFT], 1u);
        atomicAdd(&cnt[((u32)d.z) >> NPB_SHIFT], 1u);
        atomicAdd(&cnt[((u32)d.w) >> NPB_SHIFT], 1u);
    }
    for (int i = lo + m + threadIdx.x; i < hi; i += 1024)
        atomicAdd(&cnt[((u32)dst[i]) >> NPB_SHIFT], 1u);
    __syncthreads();
    for (int t = threadIdx.x; t < NBINS; t += 1024)
        blockHist[(size_t)b * NBINS + t] = cnt[t];
}

// ---------- binning phase 2a: per-bin exclusive scan over NBLK blocks ----------
__global__ __launch_bounds__(NBLK) void scan1_kernel(u32* __restrict__ blockHist,
                                                     u32* __restrict__ binTotal) {
    int j = blockIdx.x;                       // bin
    __shared__ u32 lsum[NBLK];
    int t = threadIdx.x;
    u32 v = blockHist[(size_t)t * NBINS + j];
    lsum[t] = v;
    __syncthreads();
    u32 x = v;
    for (int off = 1; off < NBLK; off <<= 1) {
        u32 y = (t >= off) ? lsum[t - off] : 0u;
        __syncthreads();
        x += y; lsum[t] = x;
        __syncthreads();
    }
    if (t == NBLK - 1) binTotal[j] = x;
    blockHist[(size_t)t * NBINS + j] = x - v;   // exclusive prefix within bin
}

// ---------- binning phase 2b: exclusive scan over bin totals ----------
__global__ void scan2_kernel(const u32* __restrict__ binTotal, u32* __restrict__ binStart) {
    if (threadIdx.x == 0) {
        u32 run = 0;
        for (int j = 0; j < NBINS; ++j) { binStart[j] = run; run += binTotal[j]; }
        binStart[NBINS] = run;
    }
}

// ---------- binning phase 3: LDS-staged scatter with coalesced flush ----------
__global__ __launch_bounds__(512) void scatter_staged(const int* __restrict__ src,
                                                      const int* __restrict__ dst,
                                                      const float* __restrict__ ew,
                                                      int E, int chunk,
                                                      const u32* __restrict__ blockHist,
                                                      const u32* __restrict__ binStart,
                                                      u64* __restrict__ binned) {
    __shared__ u32 cursor[NBINS];
    __shared__ u32 cnt[NBINS];
    __shared__ u32 off[NBINS];
    __shared__ u64 stage[CH];
    __shared__ unsigned char binOf[CH];
    int b   = blockIdx.x;
    int tid = threadIdx.x;
    for (int t = tid; t < NBINS; t += 512)
        cursor[t] = binStart[t] + blockHist[(size_t)b * NBINS + t];
    int lo = b * chunk, hiB = min(lo + chunk, E);
    for (int base = lo; base < hiB; base += CH) {
        int n = min(CH, hiB - base);
        for (int t = tid; t < NBINS; t += 512) cnt[t] = 0;
        __syncthreads();
        u32 rec[8]; float wv[8]; u32 bi[8]; u32 rk[8];
#pragma unroll
        for (int k = 0; k < 8; ++k) {
            int idx = base + k * 512 + tid;
            bi[k] = 0xFFFFFFFFu;
            if (idx < base + n) {
                u32 d  = (u32)dst[idx];
                bi[k]  = d >> NPB_SHIFT;
                rec[k] = ((u32)src[idx]) | ((d & (NPB - 1)) << 19);
                wv[k]  = ew[idx];
                rk[k]  = atomicAdd(&cnt[bi[k]], 1u);
            }
        }
        __syncthreads();
        // inclusive Hillis-Steele scan of cnt into off, then make exclusive
        if (tid < NBINS) off[tid] = cnt[tid];
        __syncthreads();
        for (int d2 = 1; d2 < 128; d2 <<= 1) {
            u32 v = 0;
            if (tid < NBINS) { v = off[tid]; if (tid >= d2) v += off[tid - d2]; }
            __syncthreads();
            if (tid < NBINS) off[tid] = v;
            __syncthreads();
        }
        if (tid < NBINS) off[tid] -= cnt[tid];
        __syncthreads();
#pragma unroll
        for (int k = 0; k < 8; ++k) {
            if (bi[k] != 0xFFFFFFFFu) {
                u32 p = off[bi[k]] + rk[k];
                stage[p] = (u64)rec[k] | ((u64)__float_as_uint(wv[k]) << 32);
                binOf[p] = (unsigned char)bi[k];
            }
        }
        __syncthreads();
        // coalesced flush: consecutive p within a bin run -> consecutive global addrs
        for (int p = tid; p < n; p += 512) {
            u32 j = binOf[p];
            binned[cursor[j] + ((u32)p - off[j])] = stage[p];
        }
        __syncthreads();
        for (int t = tid; t < NBINS; t += 512) cursor[t] += cnt[t];
        __syncthreads();
    }
}

// ---------- per-layer: gather + LDS-accumulate into per-slice partials ----------
__global__ __launch_bounds__(512) void bin_pass(const u64* __restrict__ binned,
                                                const u32* __restrict__ binStart,
                                                const float* __restrict__ hsrc,
                                                float* __restrict__ partials) {
    __shared__ float acc[NPB];
    int blk   = blockIdx.x;
    int j     = blk >> 2;            // bin
    int slice = blk & (SLICES - 1);
    for (int t = threadIdx.x; t < NPB; t += 512) acc[t] = 0.0f;
    __syncthreads();
    u32 blo = binStart[j], bhi = binStart[j + 1];
    u32 cnt = bhi - blo;
    u32 per = (cnt + SLICES - 1) / SLICES;
    u32 lo = blo + slice * per;
    u32 hi = min(lo + per, bhi);

    u32 i = lo + threadIdx.x;
    // 8-way unrolled: 8 independent record loads -> 8 gathers -> 8 LDS atomics
    for (; i + 7u * 512u < hi; i += 8u * 512u) {
        u64 e[8];
#pragma unroll
        for (int k = 0; k < 8; ++k) e[k] = __builtin_nontemporal_load(&binned[i + (u32)k * 512u]);
        float g[8];
#pragma unroll
        for (int k = 0; k < 8; ++k) g[k] = hsrc[((u32)e[k]) & 0x7FFFFu];
#pragma unroll
        for (int k = 0; k < 8; ++k)
            atomicAdd(&acc[((u32)e[k]) >> 19], g[k] * __uint_as_float((u32)(e[k] >> 32)));
    }
    for (; i < hi; i += 512) {
        u64 e = __builtin_nontemporal_load(&binned[i]);
        u32 xx = (u32)e;
        atomicAdd(&acc[xx >> 19], hsrc[xx & 0x7FFFFu] * __uint_as_float((u32)(e >> 32)));
    }
    __syncthreads();
    float* p = partials + (size_t)(j * SLICES + slice) * NPB;
    for (int t = threadIdx.x; t < NPB; t += 512)
        __builtin_nontemporal_store(acc[t], &p[t]);
}

// ---------- merge slices + bias + self-loop + relu ----------
__global__ void merge_update(const float* __restrict__ partials,
                             const float* __restrict__ selfv,
                             const float* __restrict__ wnp,  // scalar or nullptr (=1)
                             const float* __restrict__ bp,   // scalar bias
                             const float* __restrict__ wsp,  // scalar or nullptr (=1)
                             float* __restrict__ hout) {
    int n = blockIdx.x * blockDim.x + threadIdx.x;
    if (n >= N_NODES) return;
    int j = n >> NPB_SHIFT;
    int l = n & (NPB - 1);
    const float* p = partials + (size_t)j * SLICES * NPB + l;
    float sum = p[0] + p[NPB] + p[2 * NPB] + p[3 * NPB];
    float scale = wnp ? wnp[0] : 1.0f;
    float wself = wsp ? wsp[0] : 1.0f;
    hout[n] = fmaxf(sum * scale + bp[0] + selfv[n] * wself, 0.0f);
}

// ---------- fallback (global atomics), correct but slow ----------
__global__ void edge_pass(const int* __restrict__ src, const int* __restrict__ dst,
                          const float* __restrict__ ew, const float* __restrict__ h,
                          float* __restrict__ agg, const float* __restrict__ wnp, int E) {
    float scale = wnp ? wnp[0] : 1.0f;
    int stride = gridDim.x * blockDim.x;
    for (int i = blockIdx.x * blockDim.x + threadIdx.x; i < E; i += stride)
        atomicAdd(&agg[dst[i]], h[src[i]] * ew[i] * scale);
}
__global__ void node_update(const float* __restrict__ agg, const float* __restrict__ selfv,
                            const float* __restrict__ bp, const float* __restrict__ wsp,
                            float* __restrict__ hout) {
    int i = blockIdx.x * blockDim.x + threadIdx.x;
    if (i >= N_NODES) return;
    float wsc = wsp ? wsp[0] : 1.0f;
    hout[i] = fmaxf(agg[i] + bp[0] + selfv[i] * wsc, 0.0f);
}

// ---------- per-graph sum (graph_id sorted) ----------
__global__ void graph_sum(const float* __restrict__ h, const int* __restrict__ gid,
                          float* __restrict__ hg) {
    __shared__ float loc[NGRAPH];
    int t = threadIdx.x;
    if (t < NGRAPH) loc[t] = 0.0f;
    __syncthreads();
    int stride = gridDim.x * blockDim.x;
    for (int i = blockIdx.x * blockDim.x + t; i < N_NODES; i += stride)
        atomicAdd(&loc[gid[i]], h[i]);
    __syncthreads();
    if (t < NGRAPH) atomicAdd(&hg[t], loc[t]);
}

// ---------- head MLP + log_softmax ----------
__global__ void head_kernel(const float* __restrict__ hg,
                            const float* __restrict__ fc1w, const float* __restrict__ fc1b,
                            const float* __restrict__ outw, const float* __restrict__ outb,
                            float* __restrict__ out) {
    int g = threadIdx.x;
    if (g >= NGRAPH) return;
    float v = hg[g];
    float t[8];
#pragma unroll
    for (int j = 0; j < 8; ++j) {
        float z = (v * fc1w[j] + fc1b[j]) * 1000.0f;
        t[j] = 1.0f / (1.0f + expf(-z));
    }
    float o[4];
#pragma unroll
    for (int k = 0; k < 4; ++k) {
        float acc2 = outb[k];
#pragma unroll
        for (int j = 0; j < 8; ++j) acc2 += t[j] * outw[k * 8 + j];
        o[k] = fmaxf(acc2, 0.0f);
    }
    float m = fmaxf(fmaxf(o[0], o[1]), fmaxf(o[2], o[3]));
    float se = 0.0f;
#pragma unroll
    for (int k = 0; k < 4; ++k) se += expf(o[k] - m);
    float lse = m + logf(se);
#pragma unroll
    for (int k = 0; k < 4; ++k) out[g * 4 + k] = o[k] - lse;
}

extern "C" void kernel_launch(void* const* d_in, const int* in_sizes, int n_in,
                              void* d_out, int out_size, void* d_ws, size_t ws_size,
                              hipStream_t stream) {
    const float* x    = (const float*)d_in[0];
    const int*   src  = (const int*)  d_in[1];
    const int*   dst  = (const int*)  d_in[2];
    const int*   gid  = (const int*)  d_in[3];
    const float* ew   = (const float*)d_in[4];
    const float* wn0  = (const float*)d_in[6];
    const float* b0   = (const float*)d_in[7];
    const float* ws0  = (const float*)d_in[8];
    const float* wn1  = (const float*)d_in[9];
    const float* b1   = (const float*)d_in[10];
    const float* ws1  = (const float*)d_in[11];
    const float* wn2  = (const float*)d_in[12];
    const float* b2   = (const float*)d_in[13];
    const float* ws2  = (const float*)d_in[14];
    const float* fc1w = (const float*)d_in[15];
    const float* fc1b = (const float*)d_in[16];
    const float* outw = (const float*)d_in[17];
    const float* outb = (const float*)d_in[18];
    int E = in_sizes[1];

    const int BLK = 256;
    int nodeGrid = (N_NODES + BLK - 1) / BLK;
    char* ws = (char*)d_ws;

    // workspace layout
    size_t off = 0;
    u64*   binned    = (u64*)(ws + off);   off += (size_t)E * 8;
    u32*   blockHist = (u32*)(ws + off);   off += (size_t)NBLK * NBINS * 4;
    u32*   binStart  = (u32*)(ws + off);   off += (NBINS + 1) * 4;
    off = (off + 63) & ~(size_t)63;
    u32*   binTotal  = (u32*)(ws + off);   off += (NBINS + 1) * 4;
    off = (off + 63) & ~(size_t)63;
    float* partials  = (float*)(ws + off); off += (size_t)NBINS * SLICES * NPB * 4;
    float* a  = (float*)(ws + off); off += (size_t)N_NODES * 4;
    float* s  = (float*)(ws + off); off += (size_t)N_NODES * 4;
    float* h0 = (float*)(ws + off); off += (size_t)N_NODES * 4;
    float* h1 = (float*)(ws + off); off += (size_t)N_NODES * 4;
    float* hg = (float*)(ws + off); off += NGRAPH * 4;
    size_t need = off;

    if (ws_size >= need) {
        int chunk = (((E + NBLK - 1) / NBLK) + 3) & ~3;

        proj_kernel<<<nodeGrid, BLK, 0, stream>>>(x, wn0, ws0, a, s);

        hist_kernel<<<NBLK, 1024, 0, stream>>>(dst, E, chunk, blockHist);
        scan1_kernel<<<NBINS, NBLK, 0, stream>>>(blockHist, binTotal);
        scan2_kernel<<<1, 64, 0, stream>>>(binTotal, binStart);
        scatter_staged<<<NBLK, 512, 0, stream>>>(src, dst, ew, E, chunk, blockHist, binStart, binned);

        // layer 0
        bin_pass<<<NBINS * SLICES, 512, 0, stream>>>(binned, binStart, a, partials);
        merge_update<<<nodeGrid, BLK, 0, stream>>>(partials, s, nullptr, b0, nullptr, h0);
        // layer 1
        bin_pass<<<NBINS * SLICES, 512, 0, stream>>>(binned, binStart, h0, partials);
        merge_update<<<nodeGrid, BLK, 0, stream>>>(partials, h0, wn1, b1, ws1, h1);
        // layer 2 (output reuses a)
        bin_pass<<<NBINS * SLICES, 512, 0, stream>>>(binned, binStart, h1, partials);
        merge_update<<<nodeGrid, BLK, 0, stream>>>(partials, h1, wn2, b2, ws2, a);

        (void)hipMemsetAsync(hg, 0, NGRAPH * sizeof(float), stream);
        graph_sum<<<512, BLK, 0, stream>>>(a, gid, hg);
        head_kernel<<<1, 64, 0, stream>>>(hg, fc1w, fc1b, outw, outb, (float*)d_out);
    } else {
        // correct fallback: global-atomic path
        float* wsb  = (float*)d_ws;
        float* fa   = wsb;
        float* fs   = wsb + 1 * (size_t)N_NODES;
        float* fagg = wsb + 2 * (size_t)N_NODES;
        float* fh   = wsb + 3 * (size_t)N_NODES;
        float* fhg  = wsb + 4 * (size_t)N_NODES;

        proj_kernel<<<nodeGrid, BLK, 0, stream>>>(x, wn0, ws0, fa, fs);

        (void)hipMemsetAsync(fagg, 0, (size_t)N_NODES * sizeof(float), stream);
        edge_pass<<<4096, BLK, 0, stream>>>(src, dst, ew, fa, fagg, nullptr, E);
        node_update<<<nodeGrid, BLK, 0, stream>>>(fagg, fs, b0, nullptr, fh);

        (void)hipMemsetAsync(fagg, 0, (size_t)N_NODES * sizeof(float), stream);
        edge_pass<<<4096, BLK, 0, stream>>>(src, dst, ew, fh, fagg, wn1, E);
        node_update<<<nodeGrid, BLK, 0, stream>>>(fagg, fh, b1, ws1, fh);

        (void)hipMemsetAsync(fagg, 0, (size_t)N_NODES * sizeof(float), stream);
        edge_pass<<<4096, BLK, 0, stream>>>(src, dst, ew, fh, fagg, wn2, E);
        node_update<<<nodeGrid, BLK, 0, stream>>>(fagg, fh, b2, ws2, fh);

        (void)hipMemsetAsync(fhg, 0, NGRAPH * sizeof(float), stream);
        graph_sum<<<512, BLK, 0, stream>>>(fh, gid, fhg);
        head_kernel<<<1, 64, 0, stream>>>(fhg, fc1w, fc1b, outw, outb, (float*)d_out);
    }
}

// Round 7
// 408.616 us; speedup vs baseline: 5.8317x; 1.0381x over previous
//
#include <hip/hip_runtime.h>

#define N_NODES   500000
#define NGRAPH    64
#define FDIM      16
#define NPB       4096               // nodes per bin
#define NPB_SHIFT 12
#define NBINS     123                // ceil(500000/4096)
#define NBLK      1024               // binning blocks
#define CH        4096               // staged-scatter chunk (edges)
typedef unsigned int u32;
typedef unsigned long long u64;

// ---------- fused: hist (blocks 0..NBLK-1) + proj (rest) ----------
__global__ __launch_bounds__(1024) void proj_hist(const int* __restrict__ dst, int E, int chunk,
                                                  u32* __restrict__ blockHist,
                                                  const float* __restrict__ x,
                                                  const float* __restrict__ wn,
                                                  const float* __restrict__ wsf,
                                                  float* __restrict__ a,
                                                  float* __restrict__ s) {
    __shared__ u32 cnt[NBINS];
    if (blockIdx.x < NBLK) {
        for (int t = threadIdx.x; t < NBINS; t += 1024) cnt[t] = 0;
        __syncthreads();
        int b = blockIdx.x;
        int lo = b * chunk, hi = min(lo + chunk, E);
        int m = (hi - lo) & ~3;
        for (int i = lo + threadIdx.x * 4; i < lo + m; i += 4096) {
            int4 d = *(const int4*)(dst + i);
            atomicAdd(&cnt[((u32)d.x) >> NPB_SHIFT], 1u);
            atomicAdd(&cnt[((u32)d.y) >> NPB_SHIFT], 1u);
            atomicAdd(&cnt[((u32)d.z) >> NPB_SHIFT], 1u);
            atomicAdd(&cnt[((u32)d.w) >> NPB_SHIFT], 1u);
        }
        for (int i = lo + m + threadIdx.x; i < hi; i += 1024)
            atomicAdd(&cnt[((u32)dst[i]) >> NPB_SHIFT], 1u);
        __syncthreads();
        for (int t = threadIdx.x; t < NBINS; t += 1024)
            blockHist[(size_t)b * NBINS + t] = cnt[t];
    } else {
        int i = (blockIdx.x - NBLK) * 1024 + threadIdx.x;
        if (i >= N_NODES) return;
        const float4* xr = (const float4*)(x + (size_t)i * FDIM);
        float4 v0 = xr[0], v1 = xr[1], v2 = xr[2], v3 = xr[3];
        const float4* n4 = (const float4*)wn;
        const float4* s4 = (const float4*)wsf;
        float4 n0 = n4[0], n1 = n4[1], n2 = n4[2], n3 = n4[3];
        float4 w0 = s4[0], w1 = s4[1], w2 = s4[2], w3 = s4[3];
        float an = v0.x*n0.x + v0.y*n0.y + v0.z*n0.z + v0.w*n0.w
                 + v1.x*n1.x + v1.y*n1.y + v1.z*n1.z + v1.w*n1.w
                 + v2.x*n2.x + v2.y*n2.y + v2.z*n2.z + v2.w*n2.w
                 + v3.x*n3.x + v3.y*n3.y + v3.z*n3.z + v3.w*n3.w;
        float as = v0.x*w0.x + v0.y*w0.y + v0.z*w0.z + v0.w*w0.w
                 + v1.x*w1.x + v1.y*w1.y + v1.z*w1.z + v1.w*w1.w
                 + v2.x*w2.x + v2.y*w2.y + v2.z*w2.z + v2.w*w2.w
                 + v3.x*w3.x + v3.y*w3.y + v3.z*w3.z + v3.w*w3.w;
        a[i] = an;
        s[i] = as;
    }
}

// ---------- per-bin exclusive scan over NBLK blocks ----------
__global__ __launch_bounds__(NBLK) void scan1_kernel(u32* __restrict__ blockHist,
                                                     u32* __restrict__ binTotal) {
    int j = blockIdx.x;                       // bin
    __shared__ u32 lsum[NBLK];
    int t = threadIdx.x;
    u32 v = blockHist[(size_t)t * NBINS + j];
    lsum[t] = v;
    __syncthreads();
    u32 x = v;
    for (int off = 1; off < NBLK; off <<= 1) {
        u32 y = (t >= off) ? lsum[t - off] : 0u;
        __syncthreads();
        x += y; lsum[t] = x;
        __syncthreads();
    }
    if (t == NBLK - 1) binTotal[j] = x;
    blockHist[(size_t)t * NBINS + j] = x - v;   // exclusive prefix within bin
}

// ---------- parallel exclusive scan over bin totals ----------
__global__ void scan2_kernel(const u32* __restrict__ binTotal, u32* __restrict__ binStart) {
    __shared__ u32 sh[128];
    int t = threadIdx.x;
    u32 v = (t < NBINS) ? binTotal[t] : 0u;
    sh[t] = v;
    __syncthreads();
    for (int d = 1; d < 128; d <<= 1) {
        u32 y = (t >= d) ? sh[t - d] : 0u;
        __syncthreads();
        sh[t] += y;
        __syncthreads();
    }
    if (t < NBINS) binStart[t] = sh[t] - v;
    if (t == 127) binStart[NBINS] = sh[127];
}

// ---------- LDS-staged scatter with coalesced flush ----------
__global__ __launch_bounds__(512) void scatter_staged(const int* __restrict__ src,
                                                      const int* __restrict__ dst,
                                                      const float* __restrict__ ew,
                                                      int E, int chunk,
                                                      const u32* __restrict__ blockHist,
                                                      const u32* __restrict__ binStart,
                                                      u64* __restrict__ binned) {
    __shared__ u32 cursor[NBINS];
    __shared__ u32 cnt[NBINS];
    __shared__ u32 off[NBINS];
    __shared__ u64 stage[CH];
    __shared__ unsigned char binOf[CH];
    int b   = blockIdx.x;
    int tid = threadIdx.x;
    for (int t = tid; t < NBINS; t += 512)
        cursor[t] = binStart[t] + blockHist[(size_t)b * NBINS + t];
    int lo = b * chunk, hiB = min(lo + chunk, E);
    for (int base = lo; base < hiB; base += CH) {
        int n = min(CH, hiB - base);
        for (int t = tid; t < NBINS; t += 512) cnt[t] = 0;
        __syncthreads();
        u32 rec[8]; float wv[8]; u32 bi[8]; u32 rk[8];
#pragma unroll
        for (int k = 0; k < 8; ++k) {
            int idx = base + k * 512 + tid;
            bi[k] = 0xFFFFFFFFu;
            if (idx < base + n) {
                u32 d  = (u32)dst[idx];
                bi[k]  = d >> NPB_SHIFT;
                rec[k] = ((u32)src[idx]) | ((d & (NPB - 1)) << 19);
                wv[k]  = ew[idx];
                rk[k]  = atomicAdd(&cnt[bi[k]], 1u);
            }
        }
        __syncthreads();
        if (tid < NBINS) off[tid] = cnt[tid];
        __syncthreads();
        for (int d2 = 1; d2 < 128; d2 <<= 1) {
            u32 v = 0;
            if (tid < NBINS) { v = off[tid]; if (tid >= d2) v += off[tid - d2]; }
            __syncthreads();
            if (tid < NBINS) off[tid] = v;
            __syncthreads();
        }
        if (tid < NBINS) off[tid] -= cnt[tid];
        __syncthreads();
#pragma unroll
        for (int k = 0; k < 8; ++k) {
            if (bi[k] != 0xFFFFFFFFu) {
                u32 p = off[bi[k]] + rk[k];
                stage[p] = (u64)rec[k] | ((u64)__float_as_uint(wv[k]) << 32);
                binOf[p] = (unsigned char)bi[k];
            }
        }
        __syncthreads();
        for (int p = tid; p < n; p += 512) {
            u32 j = binOf[p];
            binned[cursor[j] + ((u32)p - off[j])] = stage[p];
        }
        __syncthreads();
        for (int t = tid; t < NBINS; t += 512) cursor[t] += cnt[t];
        __syncthreads();
    }
}

// ---------- per-layer: gather + LDS-accumulate into per-slice partials ----------
template<int S>
__global__ __launch_bounds__(512) void bin_pass(const u64* __restrict__ binned,
                                                const u32* __restrict__ binStart,
                                                const float* __restrict__ hsrc,
                                                float* __restrict__ partials) {
    __shared__ float acc[NPB];
    int blk   = blockIdx.x;
    int j     = blk / S;             // bin
    int slice = blk % S;
    for (int t = threadIdx.x; t < NPB; t += 512) acc[t] = 0.0f;
    __syncthreads();
    u32 blo = binStart[j], bhi = binStart[j + 1];
    u32 cnt = bhi - blo;
    u32 per = (cnt + S - 1) / S;
    u32 lo = blo + slice * per;
    u32 hi = min(lo + per, bhi);

    u32 i = lo + threadIdx.x;
    for (; i + 7u * 512u < hi; i += 8u * 512u) {
        u64 e[8];
#pragma unroll
        for (int k = 0; k < 8; ++k) e[k] = __builtin_nontemporal_load(&binned[i + (u32)k * 512u]);
        float g[8];
#pragma unroll
        for (int k = 0; k < 8; ++k) g[k] = hsrc[((u32)e[k]) & 0x7FFFFu];
#pragma unroll
        for (int k = 0; k < 8; ++k)
            atomicAdd(&acc[((u32)e[k]) >> 19], g[k] * __uint_as_float((u32)(e[k] >> 32)));
    }
    for (; i < hi; i += 512) {
        u64 e = __builtin_nontemporal_load(&binned[i]);
        u32 xx = (u32)e;
        atomicAdd(&acc[xx >> 19], hsrc[xx & 0x7FFFFu] * __uint_as_float((u32)(e >> 32)));
    }
    __syncthreads();
    float* p = partials + (size_t)(j * S + slice) * NPB;
    for (int t = threadIdx.x; t < NPB; t += 512)
        __builtin_nontemporal_store(acc[t], &p[t]);
}

// ---------- merge slices + bias + self-loop + relu ----------
template<int S>
__global__ void merge_update(const float* __restrict__ partials,
                             const float* __restrict__ selfv,
                             const float* __restrict__ wnp,
                             const float* __restrict__ bp,
                             const float* __restrict__ wsp,
                             float* __restrict__ hout) {
    int n = blockIdx.x * blockDim.x + threadIdx.x;
    if (n >= N_NODES) return;
    int j = n >> NPB_SHIFT;
    int l = n & (NPB - 1);
    const float* p = partials + (size_t)j * S * NPB + l;
    float sum = 0.0f;
#pragma unroll
    for (int k = 0; k < S; ++k) sum += __builtin_nontemporal_load(&p[k * NPB]);
    float scale = wnp ? wnp[0] : 1.0f;
    float wself = wsp ? wsp[0] : 1.0f;
    hout[n] = fmaxf(sum * scale + bp[0] + selfv[n] * wself, 0.0f);
}

// ---------- fallback (global atomics), correct but slow ----------
__global__ void edge_pass(const int* __restrict__ src, const int* __restrict__ dst,
                          const float* __restrict__ ew, const float* __restrict__ h,
                          float* __restrict__ agg, const float* __restrict__ wnp, int E) {
    float scale = wnp ? wnp[0] : 1.0f;
    int stride = gridDim.x * blockDim.x;
    for (int i = blockIdx.x * blockDim.x + threadIdx.x; i < E; i += stride)
        atomicAdd(&agg[dst[i]], h[src[i]] * ew[i] * scale);
}
__global__ void node_update(const float* __restrict__ agg, const float* __restrict__ selfv,
                            const float* __restrict__ bp, const float* __restrict__ wsp,
                            float* __restrict__ hout) {
    int i = blockIdx.x * blockDim.x + threadIdx.x;
    if (i >= N_NODES) return;
    float wsc = wsp ? wsp[0] : 1.0f;
    hout[i] = fmaxf(agg[i] + bp[0] + selfv[i] * wsc, 0.0f);
}
__global__ void proj_kernel(const float* __restrict__ x, const float* __restrict__ wn,
                            const float* __restrict__ wsf, float* __restrict__ a,
                            float* __restrict__ s) {
    int i = blockIdx.x * blockDim.x + threadIdx.x;
    if (i >= N_NODES) return;
    float an = 0.f, as = 0.f;
    for (int k = 0; k < FDIM; ++k) {
        float v = x[(size_t)i * FDIM + k];
        an += v * wn[k]; as += v * wsf[k];
    }
    a[i] = an; s[i] = as;
}

// ---------- per-graph sum (gid sorted; wave-uniform fast path) ----------
__global__ __launch_bounds__(256) void graph_sum(const float* __restrict__ h,
                                                 const int* __restrict__ gid,
                                                 float* __restrict__ hg) {
    __shared__ float loc[NGRAPH];
    int t = threadIdx.x;
    if (t < NGRAPH) loc[t] = 0.0f;
    __syncthreads();
    int nq = N_NODES / 4;                       // 125000
    int stride = gridDim.x * blockDim.x;
    for (int q = blockIdx.x * blockDim.x + t; q < nq; q += stride) {
        int4   g4 = *(const int4*)(gid + 4 * q);
        float4 h4 = *(const float4*)(h + 4 * q);
        int g0 = __shfl(g4.x, 0);
        bool uni = (g4.x == g0) & (g4.w == g0);
        if (__all(uni)) {
            float v = h4.x + h4.y + h4.z + h4.w;
#pragma unroll
            for (int o = 32; o > 0; o >>= 1) v += __shfl_down(v, o);
            if ((t & 63) == 0) atomicAdd(&loc[g0], v);
        } else {
            atomicAdd(&loc[g4.x], h4.x);
            atomicAdd(&loc[g4.y], h4.y);
            atomicAdd(&loc[g4.z], h4.z);
            atomicAdd(&loc[g4.w], h4.w);
        }
    }
    __syncthreads();
    if (t < NGRAPH) atomicAdd(&hg[t], loc[t]);
}

// ---------- head MLP + log_softmax ----------
__global__ void head_kernel(const float* __restrict__ hg,
                            const float* __restrict__ fc1w, const float* __restrict__ fc1b,
                            const float* __restrict__ outw, const float* __restrict__ outb,
                            float* __restrict__ out) {
    int g = threadIdx.x;
    if (g >= NGRAPH) return;
    float v = hg[g];
    float t[8];
#pragma unroll
    for (int j = 0; j < 8; ++j) {
        float z = (v * fc1w[j] + fc1b[j]) * 1000.0f;
        t[j] = 1.0f / (1.0f + expf(-z));
    }
    float o[4];
#pragma unroll
    for (int k = 0; k < 4; ++k) {
        float acc2 = outb[k];
#pragma unroll
        for (int j = 0; j < 8; ++j) acc2 += t[j] * outw[k * 8 + j];
        o[k] = fmaxf(acc2, 0.0f);
    }
    float m = fmaxf(fmaxf(o[0], o[1]), fmaxf(o[2], o[3]));
    float se = 0.0f;
#pragma unroll
    for (int k = 0; k < 4; ++k) se += expf(o[k] - m);
    float lse = m + logf(se);
#pragma unroll
    for (int k = 0; k < 4; ++k) out[g * 4 + k] = o[k] - lse;
}

extern "C" void kernel_launch(void* const* d_in, const int* in_sizes, int n_in,
                              void* d_out, int out_size, void* d_ws, size_t ws_size,
                              hipStream_t stream) {
    const float* x    = (const float*)d_in[0];
    const int*   src  = (const int*)  d_in[1];
    const int*   dst  = (const int*)  d_in[2];
    const int*   gid  = (const int*)  d_in[3];
    const float* ew   = (const float*)d_in[4];
    const float* wn0  = (const float*)d_in[6];
    const float* b0   = (const float*)d_in[7];
    const float* ws0  = (const float*)d_in[8];
    const float* wn1  = (const float*)d_in[9];
    const float* b1   = (const float*)d_in[10];
    const float* ws1  = (const float*)d_in[11];
    const float* wn2  = (const float*)d_in[12];
    const float* b2   = (const float*)d_in[13];
    const float* ws2  = (const float*)d_in[14];
    const float* fc1w = (const float*)d_in[15];
    const float* fc1b = (const float*)d_in[16];
    const float* outw = (const float*)d_in[17];
    const float* outb = (const float*)d_in[18];
    int E = in_sizes[1];

    const int BLK = 256;
    int nodeGrid = (N_NODES + BLK - 1) / BLK;
    char* ws = (char*)d_ws;

    // workspace layout (partials sized for chosen S)
    size_t off = 0;
    u64*   binned    = (u64*)(ws + off);   off += (size_t)E * 8;
    u32*   blockHist = (u32*)(ws + off);   off += (size_t)NBLK * NBINS * 4;
    u32*   binStart  = (u32*)(ws + off);   off += (NBINS + 1) * 4;
    off = (off + 63) & ~(size_t)63;
    u32*   binTotal  = (u32*)(ws + off);   off += (NBINS + 1) * 4;
    off = (off + 63) & ~(size_t)63;
    float* partials  = (float*)(ws + off);
    size_t base_off  = off;
    size_t nodes_bytes = 4 * (size_t)N_NODES * 4 + NGRAPH * 4;
    size_t need8 = base_off + (size_t)NBINS * 8 * NPB * 4 + nodes_bytes;
    size_t need4 = base_off + (size_t)NBINS * 4 * NPB * 4 + nodes_bytes;

    int S = (ws_size >= need8) ? 8 : ((ws_size >= need4) ? 4 : 0);

    if (S) {
        off = base_off + (size_t)NBINS * S * NPB * 4;
        float* a  = (float*)(ws + off); off += (size_t)N_NODES * 4;
        float* s  = (float*)(ws + off); off += (size_t)N_NODES * 4;
        float* h0 = (float*)(ws + off); off += (size_t)N_NODES * 4;
        float* h1 = (float*)(ws + off); off += (size_t)N_NODES * 4;
        float* hg = (float*)(ws + off);

        int chunk = (((E + NBLK - 1) / NBLK) + 3) & ~3;
        int projBlocks = (N_NODES + 1023) / 1024;

        proj_hist<<<NBLK + projBlocks, 1024, 0, stream>>>(dst, E, chunk, blockHist,
                                                          x, wn0, ws0, a, s);
        scan1_kernel<<<NBINS, NBLK, 0, stream>>>(blockHist, binTotal);
        scan2_kernel<<<1, 128, 0, stream>>>(binTotal, binStart);
        scatter_staged<<<NBLK, 512, 0, stream>>>(src, dst, ew, E, chunk, blockHist, binStart, binned);

        if (S == 8) {
            bin_pass<8><<<NBINS * 8, 512, 0, stream>>>(binned, binStart, a, partials);
            merge_update<8><<<nodeGrid, BLK, 0, stream>>>(partials, s, nullptr, b0, nullptr, h0);
            bin_pass<8><<<NBINS * 8, 512, 0, stream>>>(binned, binStart, h0, partials);
            merge_update<8><<<nodeGrid, BLK, 0, stream>>>(partials, h0, wn1, b1, ws1, h1);
            bin_pass<8><<<NBINS * 8, 512, 0, stream>>>(binned, binStart, h1, partials);
            merge_update<8><<<nodeGrid, BLK, 0, stream>>>(partials, h1, wn2, b2, ws2, a);
        } else {
            bin_pass<4><<<NBINS * 4, 512, 0, stream>>>(binned, binStart, a, partials);
            merge_update<4><<<nodeGrid, BLK, 0, stream>>>(partials, s, nullptr, b0, nullptr, h0);
            bin_pass<4><<<NBINS * 4, 512, 0, stream>>>(binned, binStart, h0, partials);
            merge_update<4><<<nodeGrid, BLK, 0, stream>>>(partials, h0, wn1, b1, ws1, h1);
            bin_pass<4><<<NBINS * 4, 512, 0, stream>>>(binned, binStart, h1, partials);
            merge_update<4><<<nodeGrid, BLK, 0, stream>>>(partials, h1, wn2, b2, ws2, a);
        }

        (void)hipMemsetAsync(hg, 0, NGRAPH * sizeof(float), stream);
        graph_sum<<<512, 256, 0, stream>>>(a, gid, hg);
        head_kernel<<<1, 64, 0, stream>>>(hg, fc1w, fc1b, outw, outb, (float*)d_out);
    } else {
        // correct fallback: global-atomic path
        float* wsb  = (float*)d_ws;
        float* fa   = wsb;
        float* fs   = wsb + 1 * (size_t)N_NODES;
        float* fagg = wsb + 2 * (size_t)N_NODES;
        float* fh   = wsb + 3 * (size_t)N_NODES;
        float* fhg  = wsb + 4 * (size_t)N_NODES;

        proj_kernel<<<nodeGrid, BLK, 0, stream>>>(x, wn0, ws0, fa, fs);

        (void)hipMemsetAsync(fagg, 0, (size_t)N_NODES * sizeof(float), stream);
        edge_pass<<<4096, BLK, 0, stream>>>(src, dst, ew, fa, fagg, nullptr, E);
        node_update<<<nodeGrid, BLK, 0, stream>>>(fagg, fs, b0, nullptr, fh);

        (void)hipMemsetAsync(fagg, 0, (size_t)N_NODES * sizeof(float), stream);
        edge_pass<<<4096, BLK, 0, stream>>>(src, dst, ew, fh, fagg, wn1, E);
        node_update<<<nodeGrid, BLK, 0, stream>>>(fagg, fh, b1, ws1, fh);

        (void)hipMemsetAsync(fagg, 0, (size_t)N_NODES * sizeof(float), stream);
        edge_pass<<<4096, BLK, 0, stream>>>(src, dst, ew, fh, fagg, wn2, E);
        node_update<<<nodeGrid, BLK, 0, stream>>>(fagg, fh, b2, ws2, fh);

        (void)hipMemsetAsync(fhg, 0, NGRAPH * sizeof(float), stream);
        graph_sum<<<512, 256, 0, stream>>>(fh, gid, fhg);
        head_kernel<<<1, 64, 0, stream>>>(fhg, fc1w, fc1b, outw, outb, (float*)d_out);
    }
}

// Round 8
// 403.481 us; speedup vs baseline: 5.9060x; 1.0127x over previous
//
#include <hip/hip_runtime.h>

#define N_NODES 500000
#define NGRAPH  64
#define FDIM    16
#define NB1     62                 // dst bins of NPB1 nodes
#define NPB1    8192
#define SH1     13
#define NB2     123                // src chunks of NPC nodes
#define NB2P    128                // padded
#define NPC     4096
#define SH2     12
#define NSUB    16                 // sub-blocks per bin for level-2 sort
#define SLC     8                  // slices per bin in bin_pass2
#define NBLK    1024               // level-1 binning blocks
#define CH      4096               // staged-scatter chunk (edges)
typedef unsigned int u32;
typedef unsigned long long u64;

// ---------- fused: level-1 hist (blocks 0..NBLK-1) + projections (rest) ----------
__global__ __launch_bounds__(1024) void proj_hist(const int* __restrict__ dst, int E, int chunk,
                                                  u32* __restrict__ blockHist,
                                                  const float* __restrict__ x,
                                                  const float* __restrict__ wn,
                                                  const float* __restrict__ wsf,
                                                  float* __restrict__ a,
                                                  float* __restrict__ s) {
    __shared__ u32 cnt[NB1];
    if (blockIdx.x < NBLK) {
        if (threadIdx.x < NB1) cnt[threadIdx.x] = 0;
        __syncthreads();
        int b = blockIdx.x;
        int lo = b * chunk, hi = min(lo + chunk, E);
        int m = (hi - lo) & ~3;
        for (int i = lo + threadIdx.x * 4; i < lo + m; i += 4096) {
            int4 d = *(const int4*)(dst + i);
            atomicAdd(&cnt[((u32)d.x) >> SH1], 1u);
            atomicAdd(&cnt[((u32)d.y) >> SH1], 1u);
            atomicAdd(&cnt[((u32)d.z) >> SH1], 1u);
            atomicAdd(&cnt[((u32)d.w) >> SH1], 1u);
        }
        for (int i = lo + m + threadIdx.x; i < hi; i += 1024)
            atomicAdd(&cnt[((u32)dst[i]) >> SH1], 1u);
        __syncthreads();
        if (threadIdx.x < NB1)
            blockHist[(size_t)b * NB1 + threadIdx.x] = cnt[threadIdx.x];
    } else {
        int i = (blockIdx.x - NBLK) * 1024 + threadIdx.x;
        if (i >= N_NODES) return;
        const float4* xr = (const float4*)(x + (size_t)i * FDIM);
        float4 v0 = xr[0], v1 = xr[1], v2 = xr[2], v3 = xr[3];
        const float4* n4 = (const float4*)wn;
        const float4* s4 = (const float4*)wsf;
        float4 n0 = n4[0], n1 = n4[1], n2 = n4[2], n3 = n4[3];
        float4 w0 = s4[0], w1 = s4[1], w2 = s4[2], w3 = s4[3];
        float an = v0.x*n0.x + v0.y*n0.y + v0.z*n0.z + v0.w*n0.w
                 + v1.x*n1.x + v1.y*n1.y + v1.z*n1.z + v1.w*n1.w
                 + v2.x*n2.x + v2.y*n2.y + v2.z*n2.z + v2.w*n2.w
                 + v3.x*n3.x + v3.y*n3.y + v3.z*n3.z + v3.w*n3.w;
        float as = v0.x*w0.x + v0.y*w0.y + v0.z*w0.z + v0.w*w0.w
                 + v1.x*w1.x + v1.y*w1.y + v1.z*w1.z + v1.w*w1.w
                 + v2.x*w2.x + v2.y*w2.y + v2.z*w2.z + v2.w*w2.w
                 + v3.x*w3.x + v3.y*w3.y + v3.z*w3.z + v3.w*w3.w;
        a[i] = an;
        s[i] = as;
    }
}

// ---------- level-1: per-bin exclusive scan over NBLK blocks ----------
__global__ __launch_bounds__(NBLK) void scan1_kernel(u32* __restrict__ blockHist,
                                                     u32* __restrict__ binTotal) {
    int j = blockIdx.x;
    __shared__ u32 lsum[NBLK];
    int t = threadIdx.x;
    u32 v = blockHist[(size_t)t * NB1 + j];
    lsum[t] = v;
    __syncthreads();
    u32 x = v;
    for (int off = 1; off < NBLK; off <<= 1) {
        u32 y = (t >= off) ? lsum[t - off] : 0u;
        __syncthreads();
        x += y; lsum[t] = x;
        __syncthreads();
    }
    if (t == NBLK - 1) binTotal[j] = x;
    blockHist[(size_t)t * NB1 + j] = x - v;
}

// ---------- level-1: exclusive scan over bin totals ----------
__global__ void scan2_kernel(const u32* __restrict__ binTotal, u32* __restrict__ binStart) {
    __shared__ u32 sh[64];
    int t = threadIdx.x;
    u32 v = (t < NB1) ? binTotal[t] : 0u;
    sh[t] = v;
    __syncthreads();
    for (int d = 1; d < 64; d <<= 1) {
        u32 y = (t >= d) ? sh[t - d] : 0u;
        __syncthreads();
        sh[t] += y;
        __syncthreads();
    }
    if (t < NB1) binStart[t] = sh[t] - v;
    if (t == 63) binStart[NB1] = sh[63];
}

// ---------- level-1: LDS-staged scatter by dst bin ----------
__global__ __launch_bounds__(512) void scatter1_staged(const int* __restrict__ src,
                                                       const int* __restrict__ dst,
                                                       const float* __restrict__ ew,
                                                       int E, int chunk,
                                                       const u32* __restrict__ blockHist,
                                                       const u32* __restrict__ binStart,
                                                       u64* __restrict__ binned) {
    __shared__ u32 cursor[64];
    __shared__ u32 cnt[64];
    __shared__ u32 off[64];
    __shared__ u64 stage[CH];
    __shared__ unsigned char binOf[CH];
    int b = blockIdx.x, tid = threadIdx.x;
    if (tid < NB1) cursor[tid] = binStart[tid] + blockHist[(size_t)b * NB1 + tid];
    int lo = b * chunk, hiB = min(lo + chunk, E);
    for (int base = lo; base < hiB; base += CH) {
        int n = min(CH, hiB - base);
        if (tid < 64) cnt[tid] = 0;
        __syncthreads();
        u32 rec[8]; float wv[8]; u32 bi[8], rk[8];
#pragma unroll
        for (int k = 0; k < 8; ++k) {
            int idx = base + k * 512 + tid;
            bi[k] = 0xFFFFFFFFu;
            if (idx < base + n) {
                u32 d  = (u32)dst[idx];
                bi[k]  = d >> SH1;
                rec[k] = ((u32)src[idx]) | ((d & (NPB1 - 1)) << 19);
                wv[k]  = ew[idx];
                rk[k]  = atomicAdd(&cnt[bi[k]], 1u);
            }
        }
        __syncthreads();
        if (tid < 64) off[tid] = cnt[tid];
        __syncthreads();
        for (int d2 = 1; d2 < 64; d2 <<= 1) {
            u32 y = 0;
            if (tid < 64 && tid >= d2) y = off[tid - d2];
            __syncthreads();
            if (tid < 64) off[tid] += y;
            __syncthreads();
        }
        if (tid < 64) off[tid] -= cnt[tid];
        __syncthreads();
#pragma unroll
        for (int k = 0; k < 8; ++k) {
            if (bi[k] != 0xFFFFFFFFu) {
                u32 p = off[bi[k]] + rk[k];
                stage[p] = (u64)rec[k] | ((u64)__float_as_uint(wv[k]) << 32);
                binOf[p] = (unsigned char)bi[k];
            }
        }
        __syncthreads();
        for (int p = tid; p < n; p += 512) {
            u32 jj = binOf[p];
            binned[cursor[jj] + ((u32)p - off[jj])] = stage[p];
        }
        __syncthreads();
        if (tid < NB1) cursor[tid] += cnt[tid];
        __syncthreads();
    }
}

// ---------- level-2: histogram of src chunks per (bin, sub) ----------
__global__ __launch_bounds__(512) void hist2_kernel(const u64* __restrict__ binned1,
                                                    const u32* __restrict__ binStart,
                                                    u32* __restrict__ hist2) {
    __shared__ u32 c2[NB2P];
    int j = blockIdx.x / NSUB, sb = blockIdx.x % NSUB;
    int tid = threadIdx.x;
    if (tid < NB2P) c2[tid] = 0;
    __syncthreads();
    u32 blo = binStart[j], bhi = binStart[j + 1];
    u32 cj = bhi - blo;
    u32 per = (cj + NSUB - 1) / NSUB;
    u32 lo = blo + sb * per;
    u32 hi = min(lo + per, bhi);
    const u32* b32 = (const u32*)binned1;
    for (u32 i = lo + tid; i < hi; i += 512)
        atomicAdd(&c2[(b32[2 * (size_t)i] & 0x7FFFFu) >> SH2], 1u);
    __syncthreads();
    if (tid < NB2P) hist2[((size_t)j * NSUB + sb) * NB2P + tid] = c2[tid];
}

// ---------- level-2: per-bin scan over (chunk, sub) ----------
__global__ __launch_bounds__(512) void scanB_kernel(const u32* __restrict__ hist2,
                                                    const u32* __restrict__ binStart,
                                                    u32* __restrict__ scatOff,
                                                    u32* __restrict__ chunkSt) {
    int j = blockIdx.x;
    __shared__ u32 tsum[512];
    int t = threadIdx.x;
    u32 base = binStart[j];
    u32 v[4]; u32 ssum = 0;
#pragma unroll
    for (int q = 0; q < 4; ++q) {
        int k = t * 4 + q;                 // k = c*NSUB + s
        int c = k >> 4, sidx = k & 15;
        u32 xv = (c < NB2) ? hist2[((size_t)j * NSUB + sidx) * NB2P + c] : 0u;
        v[q] = xv; ssum += xv;
    }
    tsum[t] = ssum;
    __syncthreads();
    u32 x = ssum;
    for (int d = 1; d < 512; d <<= 1) {
        u32 y = (t >= d) ? tsum[t - d] : 0u;
        __syncthreads();
        x += y; tsum[t] = x;
        __syncthreads();
    }
    u32 run = x - ssum;
#pragma unroll
    for (int q = 0; q < 4; ++q) {
        int k = t * 4 + q;
        int c = k >> 4, sidx = k & 15;
        if (c < NB2) {
            scatOff[((size_t)j * NSUB + sidx) * NB2P + c] = base + run;
            if (sidx == 0) chunkSt[j * (NB2 + 1) + c] = base + run;
        }
        run += v[q];
    }
    if (t == 0) chunkSt[j * (NB2 + 1) + NB2] = binStart[j + 1];
}

// ---------- level-2: staged scatter by src chunk within each bin ----------
__global__ __launch_bounds__(512) void scatter2_staged(const u64* __restrict__ binned1,
                                                       const u32* __restrict__ binStart,
                                                       const u32* __restrict__ scatOff,
                                                       u64* __restrict__ binned2) {
    __shared__ u32 cursor[NB2P];
    __shared__ u32 cnt[NB2P];
    __shared__ u32 off[NB2P];
    __shared__ u64 stage[CH];
    __shared__ unsigned char binOf[CH];
    int j = blockIdx.x / NSUB, sb = blockIdx.x % NSUB;
    int tid = threadIdx.x;
    if (tid < NB2P) cursor[tid] = (tid < NB2) ? scatOff[((size_t)j * NSUB + sb) * NB2P + tid] : 0u;
    u32 blo = binStart[j], bhi = binStart[j + 1];
    u32 cj = bhi - blo;
    u32 per = (cj + NSUB - 1) / NSUB;
    u32 lo = blo + sb * per;
    u32 hi = min(lo + per, bhi);
    for (u32 base = lo; base < hi; base += CH) {
        u32 n = min((u32)CH, hi - base);
        if (tid < NB2P) cnt[tid] = 0;
        __syncthreads();
        u64 ev[8]; u32 bi[8], rk[8];
#pragma unroll
        for (int k = 0; k < 8; ++k) {
            u32 idx = base + (u32)k * 512u + tid;
            bi[k] = 0xFFFFFFFFu;
            if (idx < base + n) {
                u64 e = binned1[idx];
                u32 r = (u32)e;
                u32 c = (r & 0x7FFFFu) >> SH2;
                bi[k] = c;
                ev[k] = ((u64)((r & (NPC - 1)) | ((r >> 19) << 12))) | (e & 0xFFFFFFFF00000000ull);
                rk[k] = atomicAdd(&cnt[c], 1u);
            }
        }
        __syncthreads();
        if (tid < NB2P) off[tid] = cnt[tid];
        __syncthreads();
        for (int d2 = 1; d2 < NB2P; d2 <<= 1) {
            u32 y = 0;
            if (tid < NB2P && tid >= d2) y = off[tid - d2];
            __syncthreads();
            if (tid < NB2P) off[tid] += y;
            __syncthreads();
        }
        if (tid < NB2P) off[tid] -= cnt[tid];
        __syncthreads();
#pragma unroll
        for (int k = 0; k < 8; ++k) {
            if (bi[k] != 0xFFFFFFFFu) {
                u32 p = off[bi[k]] + rk[k];
                stage[p] = ev[k];
                binOf[p] = (unsigned char)bi[k];
            }
        }
        __syncthreads();
        for (u32 p = tid; p < n; p += 512) {
            u32 c = binOf[p];
            binned2[cursor[c] + (p - off[c])] = stage[p];
        }
        __syncthreads();
        if (tid < NB2P) cursor[tid] += cnt[tid];
        __syncthreads();
    }
}

// ---------- per-layer: LDS-staged gather + LDS-accumulate ----------
__global__ __launch_bounds__(1024) void bin_pass2(const u64* __restrict__ binned2,
                                                  const u32* __restrict__ chunkSt,
                                                  const float* __restrict__ hsrc,
                                                  float* __restrict__ partials) {
    __shared__ float acc[NPB1];        // 32 KB
    __shared__ float chk[NPC];         // 16 KB
    __shared__ u32 cs[NB2 + 1];
    int j = blockIdx.x / SLC, sl = blockIdx.x % SLC;
    int tid = threadIdx.x;
    for (int t = tid; t < NPB1; t += 1024) acc[t] = 0.0f;
    if (tid < NB2 + 1) cs[tid] = chunkSt[j * (NB2 + 1) + tid];
    __syncthreads();
    for (int c = sl; c < NB2; c += SLC) {
        int base = c * NPC;
        int nst = min(NPC, N_NODES - base);
        if (nst == NPC) {
            float4 v = *(const float4*)(hsrc + base + tid * 4);
            *(float4*)&chk[tid * 4] = v;
        } else {
            for (int t = tid; t < nst; t += 1024) chk[t] = hsrc[base + t];
        }
        __syncthreads();
        u32 lo = cs[c], hi = cs[c + 1];
        for (u32 i = lo + tid; i < hi; i += 1024) {
            u64 e = __builtin_nontemporal_load(&binned2[i]);
            u32 r = (u32)e;
            atomicAdd(&acc[(r >> 12) & (NPB1 - 1)],
                      chk[r & (NPC - 1)] * __uint_as_float((u32)(e >> 32)));
        }
        __syncthreads();
    }
    float* p = partials + ((size_t)j * SLC + sl) * NPB1;
    for (int t = tid; t < NPB1; t += 1024)
        __builtin_nontemporal_store(acc[t], &p[t]);
}

// ---------- mid fallback: level-1 only, global gather ----------
__global__ __launch_bounds__(512) void bin_pass_g(const u64* __restrict__ binned1,
                                                  const u32* __restrict__ binStart,
                                                  const float* __restrict__ hsrc,
                                                  float* __restrict__ partials) {
    __shared__ float acc[NPB1];
    int j = blockIdx.x / SLC, sl = blockIdx.x % SLC;
    for (int t = threadIdx.x; t < NPB1; t += 512) acc[t] = 0.0f;
    __syncthreads();
    u32 blo = binStart[j], bhi = binStart[j + 1];
    u32 cj = bhi - blo;
    u32 per = (cj + SLC - 1) / SLC;
    u32 lo = blo + sl * per;
    u32 hi = min(lo + per, bhi);
    u32 i = lo + threadIdx.x;
    for (; i + 7u * 512u < hi; i += 8u * 512u) {
        u64 e[8];
#pragma unroll
        for (int k = 0; k < 8; ++k) e[k] = __builtin_nontemporal_load(&binned1[i + (u32)k * 512u]);
        float g[8];
#pragma unroll
        for (int k = 0; k < 8; ++k) g[k] = hsrc[((u32)e[k]) & 0x7FFFFu];
#pragma unroll
        for (int k = 0; k < 8; ++k)
            atomicAdd(&acc[((u32)e[k]) >> 19], g[k] * __uint_as_float((u32)(e[k] >> 32)));
    }
    for (; i < hi; i += 512) {
        u64 e = __builtin_nontemporal_load(&binned1[i]);
        atomicAdd(&acc[((u32)e) >> 19], hsrc[((u32)e) & 0x7FFFFu] * __uint_as_float((u32)(e >> 32)));
    }
    __syncthreads();
    float* p = partials + ((size_t)j * SLC + sl) * NPB1;
    for (int t = threadIdx.x; t < NPB1; t += 512)
        __builtin_nontemporal_store(acc[t], &p[t]);
}

// ---------- merge slices + bias + self-loop + relu ----------
__global__ void merge_update(const float* __restrict__ partials,
                             const float* __restrict__ selfv,
                             const float* __restrict__ wnp,
                             const float* __restrict__ bp,
                             const float* __restrict__ wsp,
                             float* __restrict__ hout) {
    int n = blockIdx.x * blockDim.x + threadIdx.x;
    if (n >= N_NODES) return;
    int j = n >> SH1;
    int l = n & (NPB1 - 1);
    const float* p = partials + (size_t)j * SLC * NPB1 + l;
    float sum = 0.0f;
#pragma unroll
    for (int k = 0; k < SLC; ++k) sum += __builtin_nontemporal_load(&p[k * NPB1]);
    float scale = wnp ? wnp[0] : 1.0f;
    float wself = wsp ? wsp[0] : 1.0f;
    hout[n] = fmaxf(sum * scale + bp[0] + selfv[n] * wself, 0.0f);
}

// ---------- smallest fallback (global atomics) ----------
__global__ void edge_pass(const int* __restrict__ src, const int* __restrict__ dst,
                          const float* __restrict__ ew, const float* __restrict__ h,
                          float* __restrict__ agg, const float* __restrict__ wnp, int E) {
    float scale = wnp ? wnp[0] : 1.0f;
    int stride = gridDim.x * blockDim.x;
    for (int i = blockIdx.x * blockDim.x + threadIdx.x; i < E; i += stride)
        atomicAdd(&agg[dst[i]], h[src[i]] * ew[i] * scale);
}
__global__ void node_update(const float* __restrict__ agg, const float* __restrict__ selfv,
                            const float* __restrict__ bp, const float* __restrict__ wsp,
                            float* __restrict__ hout) {
    int i = blockIdx.x * blockDim.x + threadIdx.x;
    if (i >= N_NODES) return;
    float wsc = wsp ? wsp[0] : 1.0f;
    hout[i] = fmaxf(agg[i] + bp[0] + selfv[i] * wsc, 0.0f);
}
__global__ void proj_kernel(const float* __restrict__ x, const float* __restrict__ wn,
                            const float* __restrict__ wsf, float* __restrict__ a,
                            float* __restrict__ s) {
    int i = blockIdx.x * blockDim.x + threadIdx.x;
    if (i >= N_NODES) return;
    float an = 0.f, as = 0.f;
    for (int k = 0; k < FDIM; ++k) {
        float v = x[(size_t)i * FDIM + k];
        an += v * wn[k]; as += v * wsf[k];
    }
    a[i] = an; s[i] = as;
}

// ---------- per-graph sum (gid sorted; wave-uniform fast path) ----------
__global__ __launch_bounds__(256) void graph_sum(const float* __restrict__ h,
                                                 const int* __restrict__ gid,
                                                 float* __restrict__ hg) {
    __shared__ float loc[NGRAPH];
    int t = threadIdx.x;
    if (t < NGRAPH) loc[t] = 0.0f;
    __syncthreads();
    int nq = N_NODES / 4;
    int stride = gridDim.x * blockDim.x;
    for (int q = blockIdx.x * blockDim.x + t; q < nq; q += stride) {
        int4   g4 = *(const int4*)(gid + 4 * q);
        float4 h4 = *(const float4*)(h + 4 * q);
        int g0 = __shfl(g4.x, 0);
        bool uni = (g4.x == g0) & (g4.w == g0);
        if (__all(uni)) {
            float v = h4.x + h4.y + h4.z + h4.w;
#pragma unroll
            for (int o = 32; o > 0; o >>= 1) v += __shfl_down(v, o);
            if ((t & 63) == 0) atomicAdd(&loc[g0], v);
        } else {
            atomicAdd(&loc[g4.x], h4.x);
            atomicAdd(&loc[g4.y], h4.y);
            atomicAdd(&loc[g4.z], h4.z);
            atomicAdd(&loc[g4.w], h4.w);
        }
    }
    __syncthreads();
    if (t < NGRAPH) atomicAdd(&hg[t], loc[t]);
}

// ---------- head MLP + log_softmax ----------
__global__ void head_kernel(const float* __restrict__ hg,
                            const float* __restrict__ fc1w, const float* __restrict__ fc1b,
                            const float* __restrict__ outw, const float* __restrict__ outb,
                            float* __restrict__ out) {
    int g = threadIdx.x;
    if (g >= NGRAPH) return;
    float v = hg[g];
    float t[8];
#pragma unroll
    for (int j = 0; j < 8; ++j) {
        float z = (v * fc1w[j] + fc1b[j]) * 1000.0f;
        t[j] = 1.0f / (1.0f + expf(-z));
    }
    float o[4];
#pragma unroll
    for (int k = 0; k < 4; ++k) {
        float acc2 = outb[k];
#pragma unroll
        for (int j = 0; j < 8; ++j) acc2 += t[j] * outw[k * 8 + j];
        o[k] = fmaxf(acc2, 0.0f);
    }
    float m = fmaxf(fmaxf(o[0], o[1]), fmaxf(o[2], o[3]));
    float se = 0.0f;
#pragma unroll
    for (int k = 0; k < 4; ++k) se += expf(o[k] - m);
    float lse = m + logf(se);
#pragma unroll
    for (int k = 0; k < 4; ++k) out[g * 4 + k] = o[k] - lse;
}

extern "C" void kernel_launch(void* const* d_in, const int* in_sizes, int n_in,
                              void* d_out, int out_size, void* d_ws, size_t ws_size,
                              hipStream_t stream) {
    const float* x    = (const float*)d_in[0];
    const int*   src  = (const int*)  d_in[1];
    const int*   dst  = (const int*)  d_in[2];
    const int*   gid  = (const int*)  d_in[3];
    const float* ew   = (const float*)d_in[4];
    const float* wn0  = (const float*)d_in[6];
    const float* b0   = (const float*)d_in[7];
    const float* ws0  = (const float*)d_in[8];
    const float* wn1  = (const float*)d_in[9];
    const float* b1   = (const float*)d_in[10];
    const float* ws1  = (const float*)d_in[11];
    const float* wn2  = (const float*)d_in[12];
    const float* b2   = (const float*)d_in[13];
    const float* ws2  = (const float*)d_in[14];
    const float* fc1w = (const float*)d_in[15];
    const float* fc1b = (const float*)d_in[16];
    const float* outw = (const float*)d_in[17];
    const float* outb = (const float*)d_in[18];
    int E = in_sizes[1];

    const int BLK = 256;
    int nodeGrid = (N_NODES + BLK - 1) / BLK;
    char* ws = (char*)d_ws;

    // workspace layout (binned2 last so mid path fits smaller ws)
    size_t off = 0;
    u64* binned1    = (u64*)(ws + off); off += (size_t)E * 8;
    u32* blockHist  = (u32*)(ws + off); off += (size_t)NBLK * NB1 * 4;
    u32* binStart   = (u32*)(ws + off); off += (NB1 + 2) * 4;
    off = (off + 63) & ~(size_t)63;
    u32* binTotal   = (u32*)(ws + off); off += (NB1 + 2) * 4;
    off = (off + 63) & ~(size_t)63;
    u32* hist2buf   = (u32*)(ws + off); off += (size_t)NB1 * NSUB * NB2P * 4;
    u32* scatOff    = (u32*)(ws + off); off += (size_t)NB1 * NSUB * NB2P * 4;
    u32* chunkSt    = (u32*)(ws + off); off += (size_t)NB1 * (NB2 + 1) * 4;
    off = (off + 63) & ~(size_t)63;
    float* partials = (float*)(ws + off); off += (size_t)NB1 * SLC * NPB1 * 4;
    float* a  = (float*)(ws + off); off += (size_t)N_NODES * 4;
    float* s  = (float*)(ws + off); off += (size_t)N_NODES * 4;
    float* h0 = (float*)(ws + off); off += (size_t)N_NODES * 4;
    float* h1 = (float*)(ws + off); off += (size_t)N_NODES * 4;
    float* hg = (float*)(ws + off); off += 256;
    off = (off + 63) & ~(size_t)63;
    size_t need_mid = off;
    u64* binned2 = (u64*)(ws + off); off += (size_t)E * 8;
    size_t need_full = off;

    if (ws_size >= need_mid) {
        bool full = (ws_size >= need_full);
        int chunk = (((E + NBLK - 1) / NBLK) + 3) & ~3;
        int projBlocks = (N_NODES + 1023) / 1024;

        proj_hist<<<NBLK + projBlocks, 1024, 0, stream>>>(dst, E, chunk, blockHist,
                                                          x, wn0, ws0, a, s);
        scan1_kernel<<<NB1, NBLK, 0, stream>>>(blockHist, binTotal);
        scan2_kernel<<<1, 64, 0, stream>>>(binTotal, binStart);
        scatter1_staged<<<NBLK, 512, 0, stream>>>(src, dst, ew, E, chunk, blockHist,
                                                  binStart, binned1);
        if (full) {
            hist2_kernel<<<NB1 * NSUB, 512, 0, stream>>>(binned1, binStart, hist2buf);
            scanB_kernel<<<NB1, 512, 0, stream>>>(hist2buf, binStart, scatOff, chunkSt);
            scatter2_staged<<<NB1 * NSUB, 512, 0, stream>>>(binned1, binStart, scatOff, binned2);

            bin_pass2<<<NB1 * SLC, 1024, 0, stream>>>(binned2, chunkSt, a, partials);
            merge_update<<<nodeGrid, BLK, 0, stream>>>(partials, s, nullptr, b0, nullptr, h0);
            bin_pass2<<<NB1 * SLC, 1024, 0, stream>>>(binned2, chunkSt, h0, partials);
            merge_update<<<nodeGrid, BLK, 0, stream>>>(partials, h0, wn1, b1, ws1, h1);
            bin_pass2<<<NB1 * SLC, 1024, 0, stream>>>(binned2, chunkSt, h1, partials);
            merge_update<<<nodeGrid, BLK, 0, stream>>>(partials, h1, wn2, b2, ws2, a);
        } else {
            bin_pass_g<<<NB1 * SLC, 512, 0, stream>>>(binned1, binStart, a, partials);
            merge_update<<<nodeGrid, BLK, 0, stream>>>(partials, s, nullptr, b0, nullptr, h0);
            bin_pass_g<<<NB1 * SLC, 512, 0, stream>>>(binned1, binStart, h0, partials);
            merge_update<<<nodeGrid, BLK, 0, stream>>>(partials, h0, wn1, b1, ws1, h1);
            bin_pass_g<<<NB1 * SLC, 512, 0, stream>>>(binned1, binStart, h1, partials);
            merge_update<<<nodeGrid, BLK, 0, stream>>>(partials, h1, wn2, b2, ws2, a);
        }

        (void)hipMemsetAsync(hg, 0, NGRAPH * sizeof(float), stream);
        graph_sum<<<512, 256, 0, stream>>>(a, gid, hg);
        head_kernel<<<1, 64, 0, stream>>>(hg, fc1w, fc1b, outw, outb, (float*)d_out);
    } else {
        // smallest fallback: global-atomic path
        float* wsb  = (float*)d_ws;
        float* fa   = wsb;
        float* fs   = wsb + 1 * (size_t)N_NODES;
        float* fagg = wsb + 2 * (size_t)N_NODES;
        float* fh   = wsb + 3 * (size_t)N_NODES;
        float* fhg  = wsb + 4 * (size_t)N_NODES;

        proj_kernel<<<nodeGrid, BLK, 0, stream>>>(x, wn0, ws0, fa, fs);

        (void)hipMemsetAsync(fagg, 0, (size_t)N_NODES * sizeof(float), stream);
        edge_pass<<<4096, BLK, 0, stream>>>(src, dst, ew, fa, fagg, nullptr, E);
        node_update<<<nodeGrid, BLK, 0, stream>>>(fagg, fs, b0, nullptr, fh);

        (void)hipMemsetAsync(fagg, 0, (size_t)N_NODES * sizeof(float), stream);
        edge_pass<<<4096, BLK, 0, stream>>>(src, dst, ew, fh, fagg, wn1, E);
        node_update<<<nodeGrid, BLK, 0, stream>>>(fagg, fh, b1, ws1, fh);

        (void)hipMemsetAsync(fagg, 0, (size_t)N_NODES * sizeof(float), stream);
        edge_pass<<<4096, BLK, 0, stream>>>(src, dst, ew, fh, fagg, wn2, E);
        node_update<<<nodeGrid, BLK, 0, stream>>>(fagg, fh, b2, ws2, fh);

        (void)hipMemsetAsync(fhg, 0, NGRAPH * sizeof(float), stream);
        graph_sum<<<512, 256, 0, stream>>>(fh, gid, fhg);
        head_kernel<<<1, 64, 0, stream>>>(fhg, fc1w, fc1b, outw, outb, (float*)d_out);
    }
}